// Round 4
// baseline (398.080 us; speedup 1.0000x reference)
//
#include <hip/hip_runtime.h>

// TriangleAttention (starting node), MI355X gfx950.  Round 5.
// B=1, N=320, DIM=128, HEADS=4, DH=64, INNER=256. fp32 I/O, bf16 MFMA inside.
//
// Round-5 = round-2 (passing, 334us) + two changes:
//  * pkbf: PROVEN bit-math RTNE pack (v_cvt_pk_bf16_f32 asm NaN'd in r3/r4 -> dropped).
//  * softmax in exp2 domain: SCALE*log2e folded into score FMA, bias pre-scaled
//    by log2e in x2bf_bias, exp -> exp2 (pure identity).
//  * attn geometry: 512 thr/8 waves -> 640 thr/10 waves. Phase-1 20 tasks = 2/wave
//    (was 3 on waves 0-3); phase-2 10 tasks = 1/wave (was 2 on waves 0-1).
//    Critical path 3*T1+2*T2 -> 2*T1+1*T2; +25% resident waves (LDS still 1 WG/CU).
//
// Pipeline:
//  x2bf_bias: one wave per (q,k) pair: X fp32 -> Xbf (bf16, ws) + fp32 bias GEMV
//             (pre-scaled by log2e) into Bws[h][q][k] (wave shfl-reduce).
//  wpack:     Wqkv fp32 -> Wqkvt bf16 [col 768][din 128] (ws).
//  attn:      per (h,i), 640 thr / 10 waves. LDS: K,Vt,W (140 KB).
//             Phase 1: 20 balanced wave-tasks build K/Vt.
//             Phase 2: 10 balanced q-tile tasks: Q-proj (D->B-frag via
//             shfl_xor(32)), scores^T, lane-local softmax (exp2 domain), PV with
//             register-built P-frags. Only 2 __syncthreads total.
//  proj:      Out = Attn @ Wout + bout. Attn bf16 lives IN d_out.

#define NN     320
#define DIMD   128
#define NHEADS 4
#define DH     64
#define INNERD 256
#define NPAIR  (NN*NN)
#define SCALE  0.125f
#define LOG2E  1.44269504f
#define SCL2   0.18033688f   // 0.125 * log2(e)

typedef __attribute__((ext_vector_type(8)))  short    bf16x8;
typedef __attribute__((ext_vector_type(16))) float    f32x16;
typedef __attribute__((ext_vector_type(4)))  unsigned u32x4;

#define MFMA32(a,b,c) __builtin_amdgcn_mfma_f32_32x32x16_bf16((a),(b),(c),0,0,0)

#if defined(__has_builtin)
# if __has_builtin(__builtin_amdgcn_exp2f)
#  define HAVE_EXP2 1
# endif
#endif

// pack two f32 -> 2x bf16 (RTNE), proven bit-math version
__device__ __forceinline__ unsigned pkbf(float lo, float hi){
  unsigned a = __builtin_bit_cast(unsigned, lo);
  unsigned b = __builtin_bit_cast(unsigned, hi);
  a = (a + 0x7fffu + ((a>>16)&1u)) >> 16;
  b = (b + 0x7fffu + ((b>>16)&1u)) >> 16;
  return (a & 0xffffu) | (b<<16);
}
__device__ __forceinline__ unsigned short bf1(float f){
  unsigned u = __builtin_bit_cast(unsigned, f);
  return (unsigned short)((u + 0x7fffu + ((u>>16)&1u)) >> 16);
}
__device__ __forceinline__ float ex2(float x){
#ifdef HAVE_EXP2
  return __builtin_amdgcn_exp2f(x);
#else
  return exp2f(x);
#endif
}
__device__ __forceinline__ f32x16 z16(){
  f32x16 v;
#pragma unroll
  for (int k = 0; k < 16; ++k) v[k] = 0.0f;
  return v;
}

// ---------------------------------------------------------------------------
// x2bf_bias: wave per pair p=(q,k). Read 128 fp32 (float2/lane), write 64 dwords
// bf16 (XBF), and 4-head bias dot via fp32 shfl-reduce into Bws[h][q][k].
// Bias pre-scaled by log2(e) so attn softmax can use exp2 directly.
// ---------------------------------------------------------------------------
template<bool XBF>
__global__ void __launch_bounds__(256) x2bf_bias(const float* __restrict__ X,
                                                 const float* __restrict__ Wbias,
                                                 float* __restrict__ Bws,
                                                 unsigned* __restrict__ XbfU){
  const int tid  = threadIdx.x;
  const int lane = tid & 63;
  const int p    = blockIdx.x*4 + (tid >> 6);
  const int q    = p / NN, k = p - q*NN;
  float2 v = ((const float2*)(X + (size_t)p*DIMD))[lane];
  float4 w0 = ((const float4*)Wbias)[2*lane];
  float4 w1 = ((const float4*)Wbias)[2*lane+1];
  float4 s;
  s.x = v.x*w0.x + v.y*w1.x;
  s.y = v.x*w0.y + v.y*w1.y;
  s.z = v.x*w0.z + v.y*w1.z;
  s.w = v.x*w0.w + v.y*w1.w;
  if (XBF) XbfU[(size_t)p*64 + lane] = pkbf(v.x, v.y);
#pragma unroll
  for (int off = 32; off >= 1; off >>= 1){
    s.x += __shfl_xor(s.x, off);
    s.y += __shfl_xor(s.y, off);
    s.z += __shfl_xor(s.z, off);
    s.w += __shfl_xor(s.w, off);
  }
  if (lane == 0){
    Bws[(size_t)0*NPAIR + q*NN + k] = s.x*LOG2E;
    Bws[(size_t)1*NPAIR + q*NN + k] = s.y*LOG2E;
    Bws[(size_t)2*NPAIR + q*NN + k] = s.z*LOG2E;
    Bws[(size_t)3*NPAIR + q*NN + k] = s.w*LOG2E;
  }
}

// ---------------------------------------------------------------------------
// wpack: Wqkvt[c*128+d] = bf16(Wqkv[d*768+c]).  Coalesced reads, tiny scatter.
// ---------------------------------------------------------------------------
__global__ void __launch_bounds__(256) wpack(const float* __restrict__ Wqkv,
                                             unsigned short* __restrict__ Wqkvt){
  const int idx = blockIdx.x*256 + threadIdx.x;   // < 98304
  const int c = idx % 768, d = idx / 768;
  Wqkvt[c*DIMD + d] = bf1(Wqkv[idx]);
}

// ---------------------------------------------------------------------------
// attn kernel.  LDS map (bytes):
//   K   [320 j][64 d]  stride 144 :      0 ..  46080
//   Vt  [64 d][320 j]  stride 656 :  46080 ..  88064
//   W   [192 col][128 din] str 272:  88064 .. 140288   (q:0-63, k:64-127, v:128-191)
// ---------------------------------------------------------------------------
#define KOFF   0
#define VTOFF  46080
#define WOFF   88064
#define LDS_A  140288
#define KSTR   144
#define VTSTR  656
#define WSTR   272
#define NTHR   640
#define NWAVE  10

template<bool XBF>
__device__ __forceinline__ bf16x8 xfrag(const float* Xf, const unsigned short* Xb,
                                        int row, int ks, int coff, int half){
  if constexpr (XBF){
    return *(const bf16x8*)((const char*)Xb + (size_t)row*256 + ks*32 + coff);
  } else {
    const float* p = Xf + (size_t)row*DIMD + ks*16 + half*8;
    float4 x0 = ((const float4*)p)[0], x1 = ((const float4*)p)[1];
    u32x4 v; v[0]=pkbf(x0.x,x0.y); v[1]=pkbf(x0.z,x0.w); v[2]=pkbf(x1.x,x1.y); v[3]=pkbf(x1.z,x1.w);
    return __builtin_bit_cast(bf16x8, v);
  }
}

template<bool XBF>
__global__ void __launch_bounds__(NTHR) attn_kernel(const float* __restrict__ X,
                                                    const unsigned short* __restrict__ Xbf,
                                                    const float* __restrict__ Wqkv,
                                                    const unsigned short* __restrict__ Wqkvt,
                                                    const float* __restrict__ Bws,
                                                    unsigned short* __restrict__ AttnOut){
  extern __shared__ char sm[];
  const int h = blockIdx.x, i = blockIdx.y;
  const int tid  = threadIdx.x;
  const int w    = tid >> 6;          // 0..9
  const int lane = tid & 63;
  const int half = lane >> 5;
  const int l31  = lane & 31;
  const int coff = half*16;

  // ---- stage W (q|k|v cols for this head), transposed [col][din] bf16
  if (XBF){
    for (int idx = tid; idx < 192*16; idx += NTHR){
      const int col = idx >> 4, seg = idx & 15;
      const int gcol = (col < 64)  ? (h*DH + col)
                     : (col < 128) ? (INNERD   + h*DH + (col-64))
                                   : (2*INNERD + h*DH + (col-128));
      u32x4 v = *(const u32x4*)(Wqkvt + (size_t)gcol*DIMD + seg*8);
      *(u32x4*)(sm + WOFF + (size_t)col*WSTR + seg*16) = v;
    }
  } else if (tid < 192){
    const int col  = tid;
    const int gcol = (col < 64)  ? (h*DH + col)
                   : (col < 128) ? (INNERD   + h*DH + (col-64))
                                 : (2*INNERD + h*DH + (col-128));
    char* dst = sm + WOFF + (size_t)col*WSTR;
    for (int d0 = 0; d0 < DIMD; d0 += 8){
      u32x4 v;
      v[0] = pkbf(Wqkv[(size_t)(d0+0)*768 + gcol], Wqkv[(size_t)(d0+1)*768 + gcol]);
      v[1] = pkbf(Wqkv[(size_t)(d0+2)*768 + gcol], Wqkv[(size_t)(d0+3)*768 + gcol]);
      v[2] = pkbf(Wqkv[(size_t)(d0+4)*768 + gcol], Wqkv[(size_t)(d0+5)*768 + gcol]);
      v[3] = pkbf(Wqkv[(size_t)(d0+6)*768 + gcol], Wqkv[(size_t)(d0+7)*768 + gcol]);
      *(u32x4*)(dst + d0*2) = v;
    }
  }
  __syncthreads();

  // ============ phase 1: 20 balanced wave-tasks (10 K, 10 V), 2 per wave ======
#pragma unroll
  for (int r = 0; r < 2; ++r){
    const int t = w + NWAVE*r;          // 0..19 exactly
    const bool isK = (t < 10);
    const int  jt  = isK ? t : t - 10;
    const int  jrow = jt*32 + l31;
    const int  grow = i*NN + jrow;
    f32x16 acc0 = z16(), acc1 = z16();
    if (isK){
      const char* A0 = sm + WOFF + (size_t)(64 + l31)*WSTR;
      const char* A1 = sm + WOFF + (size_t)(96 + l31)*WSTR;
#pragma unroll
      for (int ks = 0; ks < 8; ++ks){
        bf16x8 b  = xfrag<XBF>(X, Xbf, grow, ks, coff, half);
        bf16x8 a0 = *(const bf16x8*)(A0 + ks*32 + coff);
        bf16x8 a1 = *(const bf16x8*)(A1 + ks*32 + coff);
        acc0 = MFMA32(a0, b, acc0);
        acc1 = MFMA32(a1, b, acc1);
      }
#pragma unroll
      for (int rq = 0; rq < 4; ++rq){
        uint2 v0, v1;
        v0.x = pkbf(acc0[4*rq+0], acc0[4*rq+1]); v0.y = pkbf(acc0[4*rq+2], acc0[4*rq+3]);
        v1.x = pkbf(acc1[4*rq+0], acc1[4*rq+1]); v1.y = pkbf(acc1[4*rq+2], acc1[4*rq+3]);
        *(uint2*)(sm + KOFF + (size_t)jrow*KSTR +      (8*rq + 4*half)*2) = v0;
        *(uint2*)(sm + KOFF + (size_t)jrow*KSTR + 64 + (8*rq + 4*half)*2) = v1;
      }
    } else {
      const char* B0 = sm + WOFF + (size_t)(128 + l31)*WSTR;
      const char* B1 = sm + WOFF + (size_t)(160 + l31)*WSTR;
#pragma unroll
      for (int ks = 0; ks < 8; ++ks){
        bf16x8 a  = xfrag<XBF>(X, Xbf, grow, ks, coff, half);
        bf16x8 b0 = *(const bf16x8*)(B0 + ks*32 + coff);
        bf16x8 b1 = *(const bf16x8*)(B1 + ks*32 + coff);
        acc0 = MFMA32(a, b0, acc0);
        acc1 = MFMA32(a, b1, acc1);
      }
#pragma unroll
      for (int rq = 0; rq < 4; ++rq){
        uint2 v0, v1;
        v0.x = pkbf(acc0[4*rq+0], acc0[4*rq+1]); v0.y = pkbf(acc0[4*rq+2], acc0[4*rq+3]);
        v1.x = pkbf(acc1[4*rq+0], acc1[4*rq+1]); v1.y = pkbf(acc1[4*rq+2], acc1[4*rq+3]);
        *(uint2*)(sm + VTOFF + (size_t)(     l31)*VTSTR + (jt*32 + 8*rq + 4*half)*2) = v0;
        *(uint2*)(sm + VTOFF + (size_t)(32 + l31)*VTSTR + (jt*32 + 8*rq + 4*half)*2) = v1;
      }
    }
  }
  __syncthreads();

  // ============ phase 2: 10 balanced q-tile wave-tasks, 1 per wave ============
  {
    const int qt = w;                   // 0..9
    const int q = qt*32 + l31;
    // ---- Q-proj: D col = q, rows = d
    f32x16 qa0 = z16(), qa1 = z16();
#pragma unroll
    for (int ks = 0; ks < 8; ++ks){
      bf16x8 b  = xfrag<XBF>(X, Xbf, i*NN + q, ks, coff, half);
      bf16x8 a0 = *(const bf16x8*)(sm + WOFF + (size_t)(     l31)*WSTR + ks*32 + coff);
      bf16x8 a1 = *(const bf16x8*)(sm + WOFF + (size_t)(32 + l31)*WSTR + ks*32 + coff);
      qa0 = MFMA32(a0, b, qa0);
      qa1 = MFMA32(a1, b, qa1);
    }
    // ---- build qf[4] (B-frags over d) in-register from D-layout via shfl_xor(32)
    bf16x8 qf[4];
    {
      unsigned a0 = pkbf(qa0[0],qa0[1]),  a0b = pkbf(qa0[2],qa0[3]);
      unsigned a1 = pkbf(qa0[4],qa0[5]),  a1b = pkbf(qa0[6],qa0[7]);
      unsigned a2 = pkbf(qa0[8],qa0[9]),  a2b = pkbf(qa0[10],qa0[11]);
      unsigned a3 = pkbf(qa0[12],qa0[13]),a3b = pkbf(qa0[14],qa0[15]);
      unsigned b0 = pkbf(qa1[0],qa1[1]),  b0b = pkbf(qa1[2],qa1[3]);
      unsigned b1 = pkbf(qa1[4],qa1[5]),  b1b = pkbf(qa1[6],qa1[7]);
      unsigned b2 = pkbf(qa1[8],qa1[9]),  b2b = pkbf(qa1[10],qa1[11]);
      unsigned b3 = pkbf(qa1[12],qa1[13]),b3b = pkbf(qa1[14],qa1[15]);
      unsigned sa0=__shfl_xor(a0,32), sa0b=__shfl_xor(a0b,32);
      unsigned sa1=__shfl_xor(a1,32), sa1b=__shfl_xor(a1b,32);
      unsigned sa2=__shfl_xor(a2,32), sa2b=__shfl_xor(a2b,32);
      unsigned sa3=__shfl_xor(a3,32), sa3b=__shfl_xor(a3b,32);
      unsigned sb0=__shfl_xor(b0,32), sb0b=__shfl_xor(b0b,32);
      unsigned sb1=__shfl_xor(b1,32), sb1b=__shfl_xor(b1b,32);
      unsigned sb2=__shfl_xor(b2,32), sb2b=__shfl_xor(b2b,32);
      unsigned sb3=__shfl_xor(b3,32), sb3b=__shfl_xor(b3b,32);
      u32x4 f;
      if (half == 0){
        f[0]=a0; f[1]=a0b; f[2]=sa0; f[3]=sa0b; qf[0]=__builtin_bit_cast(bf16x8,f);
        f[0]=a2; f[1]=a2b; f[2]=sa2; f[3]=sa2b; qf[1]=__builtin_bit_cast(bf16x8,f);
        f[0]=b0; f[1]=b0b; f[2]=sb0; f[3]=sb0b; qf[2]=__builtin_bit_cast(bf16x8,f);
        f[0]=b2; f[1]=b2b; f[2]=sb2; f[3]=sb2b; qf[3]=__builtin_bit_cast(bf16x8,f);
      } else {
        f[0]=sa1; f[1]=sa1b; f[2]=a1; f[3]=a1b; qf[0]=__builtin_bit_cast(bf16x8,f);
        f[0]=sa3; f[1]=sa3b; f[2]=a3; f[3]=a3b; qf[1]=__builtin_bit_cast(bf16x8,f);
        f[0]=sb1; f[1]=sb1b; f[2]=b1; f[3]=b1b; qf[2]=__builtin_bit_cast(bf16x8,f);
        f[0]=sb3; f[1]=sb3b; f[2]=b3; f[3]=b3b; qf[3]=__builtin_bit_cast(bf16x8,f);
      }
    }
    // ---- scores^T: S[j][q], D col = q = l31, rows = j
    f32x16 S[10];
#pragma unroll
    for (int jt = 0; jt < 10; ++jt) S[jt] = z16();
#pragma unroll
    for (int jt = 0; jt < 10; ++jt){
#pragma unroll
      for (int c = 0; c < 4; ++c){
        bf16x8 a = *(const bf16x8*)(sm + KOFF + (size_t)(jt*32 + l31)*KSTR + c*32 + coff);
        S[jt] = MFMA32(a, qf[c], S[jt]);
      }
    }
    // ---- scale + bias in exp2 domain (float4 per rq) + softmax over j
    const float4* Bf = (const float4*)(Bws + (size_t)h*NPAIR + (size_t)q*NN);
    float m = -3.0e38f;
#pragma unroll
    for (int jt = 0; jt < 10; ++jt){
#pragma unroll
      for (int rq = 0; rq < 4; ++rq){
        float4 bv = Bf[jt*8 + 2*rq + half];
        float v0 = S[jt][4*rq+0]*SCL2 + bv.x;
        float v1 = S[jt][4*rq+1]*SCL2 + bv.y;
        float v2 = S[jt][4*rq+2]*SCL2 + bv.z;
        float v3 = S[jt][4*rq+3]*SCL2 + bv.w;
        S[jt][4*rq+0]=v0; S[jt][4*rq+1]=v1; S[jt][4*rq+2]=v2; S[jt][4*rq+3]=v3;
        m = fmaxf(m, fmaxf(fmaxf(v0,v1), fmaxf(v2,v3)));
      }
    }
    m = fmaxf(m, __shfl_xor(m, 32));
    float l = 0.0f;
#pragma unroll
    for (int jt = 0; jt < 10; ++jt){
#pragma unroll
      for (int k = 0; k < 16; ++k){
        float e = ex2(S[jt][k] - m);
        S[jt][k] = e;
        l += e;
      }
    }
    l += __shfl_xor(l, 32);
    const float rl = 1.0f / l;
    // ---- PV: O^T[d][q] += Vt[d][j] * P^T[j][q]; P-frags from S regs via shfl.
    f32x16 o0 = z16(), o1 = z16();
#pragma unroll
    for (int jt = 0; jt < 10; ++jt){
      unsigned P0a = pkbf(S[jt][0], S[jt][1]),  P0b = pkbf(S[jt][2], S[jt][3]);
      unsigned P1a = pkbf(S[jt][4], S[jt][5]),  P1b = pkbf(S[jt][6], S[jt][7]);
      unsigned P2a = pkbf(S[jt][8], S[jt][9]),  P2b = pkbf(S[jt][10],S[jt][11]);
      unsigned P3a = pkbf(S[jt][12],S[jt][13]), P3b = pkbf(S[jt][14],S[jt][15]);
      unsigned s0a = __shfl_xor(P0a,32), s0b = __shfl_xor(P0b,32);
      unsigned s1a = __shfl_xor(P1a,32), s1b = __shfl_xor(P1b,32);
      unsigned s2a = __shfl_xor(P2a,32), s2b = __shfl_xor(P2b,32);
      unsigned s3a = __shfl_xor(P3a,32), s3b = __shfl_xor(P3b,32);
      u32x4 fe, fo;
      if (half == 0){ fe[0]=P0a; fe[1]=P0b; fe[2]=s0a; fe[3]=s0b;
                      fo[0]=P2a; fo[1]=P2b; fo[2]=s2a; fo[3]=s2b; }
      else          { fe[0]=s1a; fe[1]=s1b; fe[2]=P1a; fe[3]=P1b;
                      fo[0]=s3a; fo[1]=s3b; fo[2]=P3a; fo[3]=P3b; }
      bf16x8 pe = __builtin_bit_cast(bf16x8, fe);
      bf16x8 po = __builtin_bit_cast(bf16x8, fo);
      bf16x8 va0e = *(const bf16x8*)(sm + VTOFF + (size_t)(     l31)*VTSTR + jt*64 + coff);
      bf16x8 va1e = *(const bf16x8*)(sm + VTOFF + (size_t)(32 + l31)*VTSTR + jt*64 + coff);
      bf16x8 va0o = *(const bf16x8*)(sm + VTOFF + (size_t)(     l31)*VTSTR + jt*64 + 32 + coff);
      bf16x8 va1o = *(const bf16x8*)(sm + VTOFF + (size_t)(32 + l31)*VTSTR + jt*64 + 32 + coff);
      o0 = MFMA32(va0e, pe, o0);
      o1 = MFMA32(va1e, pe, o1);
      o0 = MFMA32(va0o, po, o0);
      o1 = MFMA32(va1o, po, o1);
    }
    // ---- epilogue
    const size_t rowbase = (((size_t)i*NN) + q)*INNERD + h*DH;
#pragma unroll
    for (int rq = 0; rq < 4; ++rq){
      const int dd = 8*rq + 4*half;
      uint2 v0, v1;
      v0.x = pkbf(o0[4*rq+0]*rl, o0[4*rq+1]*rl); v0.y = pkbf(o0[4*rq+2]*rl, o0[4*rq+3]*rl);
      v1.x = pkbf(o1[4*rq+0]*rl, o1[4*rq+1]*rl); v1.y = pkbf(o1[4*rq+2]*rl, o1[4*rq+3]*rl);
      *(uint2*)(AttnOut + rowbase + dd)      = v0;
      *(uint2*)(AttnOut + rowbase + 32 + dd) = v1;
    }
  }
}

// ---------------------------------------------------------------------------
// proj: Out = Attn @ Wout + bout.  LDS = W^T only (67.6 KB -> 2 WG/CU).
// A-frags straight from global; wave reads exactly the 32 rows it later writes
// (program-order read-before-write => alias-safe with Attn in d_out).
// ---------------------------------------------------------------------------
#define B_WSTR 528
#define LDS_P  67584

__global__ void __launch_bounds__(256, 2) proj_kernel(const unsigned short* Attn,
                                                      const float* __restrict__ Wout,
                                                      const float* __restrict__ bout,
                                                      float* Out){
  extern __shared__ char sm[];
  const int tid = threadIdx.x, w = tid>>6, lane = tid&63, half = lane>>5, l31 = lane&31;
  const int coff = half*16;
  const size_t r0 = (size_t)blockIdx.x * 128;
  if (tid < 128){                            // stage Wout^T [col][din] bf16
    const int col = tid;
    char* dst = sm + (size_t)col*B_WSTR;
    for (int d0 = 0; d0 < 256; d0 += 8){
      u32x4 v;
      v[0] = pkbf(Wout[(size_t)(d0+0)*DIMD + col], Wout[(size_t)(d0+1)*DIMD + col]);
      v[1] = pkbf(Wout[(size_t)(d0+2)*DIMD + col], Wout[(size_t)(d0+3)*DIMD + col]);
      v[2] = pkbf(Wout[(size_t)(d0+4)*DIMD + col], Wout[(size_t)(d0+5)*DIMD + col]);
      v[3] = pkbf(Wout[(size_t)(d0+6)*DIMD + col], Wout[(size_t)(d0+7)*DIMD + col]);
      *(u32x4*)(dst + d0*2) = v;
    }
  }
  __syncthreads();
  f32x16 acc[4];
#pragma unroll
  for (int nt = 0; nt < 4; ++nt){
    float bv = bout[nt*32 + l31];
#pragma unroll
    for (int k = 0; k < 16; ++k) acc[nt][k] = bv;
  }
  const char* Ab = (const char*)Attn + (r0 + w*32 + l31)*512;
#pragma unroll
  for (int ks = 0; ks < 16; ++ks){
    bf16x8 a = *(const bf16x8*)(Ab + ks*32 + coff);
#pragma unroll
    for (int nt = 0; nt < 4; ++nt){
      bf16x8 b = *(const bf16x8*)(sm + (size_t)(nt*32 + l31)*B_WSTR + ks*32 + coff);
      acc[nt] = MFMA32(a, b, acc[nt]);
    }
  }
#pragma unroll
  for (int nt = 0; nt < 4; ++nt){
    const int c = nt*32 + l31;
#pragma unroll
    for (int rq = 0; rq < 4; ++rq){
#pragma unroll
      for (int r = 0; r < 4; ++r){
        const int rr = w*32 + 8*rq + 4*half + r;
        Out[(r0 + rr)*DIMD + c] = acc[nt][4*rq + r];
      }
    }
  }
}

// ---------------------------------------------------------------------------
extern "C" void kernel_launch(void* const* d_in, const int* in_sizes, int n_in,
                              void* d_out, int out_size, void* d_ws, size_t ws_size,
                              hipStream_t stream){
  const float* X     = (const float*)d_in[0];
  const float* Wqkv  = (const float*)d_in[1];
  const float* Wout  = (const float*)d_in[2];
  const float* bout  = (const float*)d_in[3];
  const float* Wbias = (const float*)d_in[4];
  float* Out = (float*)d_out;

  // ws layout: Bws fp32 [0,1638400) | Xbf bf16 [1638400,27852800) | Wqkvt [.., 28049408)
  float*          Bws   = (float*)d_ws;
  unsigned short* Xbf   = (unsigned short*)((char*)d_ws + 1638400);
  unsigned*       XbfU  = (unsigned*)Xbf;
  unsigned short* Wqkvt = (unsigned short*)((char*)d_ws + 27852800);
  const bool use_bf = (ws_size >= (size_t)28049408);

  unsigned short* Attn = (unsigned short*)d_out;   // bf16 intermediate lives in d_out

  (void)hipFuncSetAttribute((const void*)proj_kernel,
                            hipFuncAttributeMaxDynamicSharedMemorySize, LDS_P);
  if (use_bf){
    (void)hipFuncSetAttribute((const void*)attn_kernel<true>,
                              hipFuncAttributeMaxDynamicSharedMemorySize, LDS_A);
    x2bf_bias<true><<<NPAIR/4, 256, 0, stream>>>(X, Wbias, Bws, XbfU);
    wpack<<<768*DIMD/256, 256, 0, stream>>>(Wqkv, Wqkvt);
    attn_kernel<true><<<dim3(NHEADS, NN), NTHR, LDS_A, stream>>>(X, Xbf, Wqkv, Wqkvt, Bws, Attn);
  } else {
    (void)hipFuncSetAttribute((const void*)attn_kernel<false>,
                              hipFuncAttributeMaxDynamicSharedMemorySize, LDS_A);
    x2bf_bias<false><<<NPAIR/4, 256, 0, stream>>>(X, Wbias, Bws, nullptr);
    attn_kernel<false><<<dim3(NHEADS, NN), NTHR, LDS_A, stream>>>(X, nullptr, Wqkv, nullptr, Bws, Attn);
  }
  proj_kernel<<<NPAIR/128, 256, LDS_P, stream>>>(Attn, Wout, bout, Out);
}

// Round 5
// 397.929 us; speedup vs baseline: 1.0004x; 1.0004x over previous
//
#include <hip/hip_runtime.h>

// TriangleAttention (starting node), MI355X gfx950.  Round 6.
// B=1, N=320, DIM=128, HEADS=4, DH=64, INNER=256. fp32 I/O, bf16 MFMA inside.
//
// Round-6 = round-5 + ONE fix: __launch_bounds__(640, 3).
//   r5's __launch_bounds__(640) let the backend target ~6 waves/EU -> 84 VGPRs
//   -> S[10] f32x16 spilled to scratch (WRITE_SIZE 103->425 MB, FETCH 87->205 MB,
//   attn 200->263us). 640-thread block needs 3 waves on 2 SIMDs => VGPR cap
//   512/3=170; min-waves/EU=3 sets exactly that cap, no spill (r2 needed 128).
//
// Carried from r5:
//  * pkbf: proven bit-math RTNE pack (v_cvt_pk_bf16_f32 asm NaN'd r3/r4 -> banned).
//  * softmax in exp2 domain (bias pre-scaled by log2e; exp -> exp2). Verified r5.
//  * attn geometry 640 thr / 10 waves: phase-1 20 tasks = 2/wave, phase-2
//    10 tasks = 1/wave (balanced; was 3+2 worst-case on 8 waves).
//
// Pipeline:
//  x2bf_bias: one wave per (q,k) pair: X fp32 -> Xbf (bf16, ws) + fp32 bias GEMV
//             (pre-scaled by log2e) into Bws[h][q][k] (wave shfl-reduce).
//  wpack:     Wqkv fp32 -> Wqkvt bf16 [col 768][din 128] (ws).
//  attn:      per (h,i), 640 thr / 10 waves. LDS: K,Vt,W (140 KB).
//             Phase 1: 20 balanced wave-tasks build K/Vt.
//             Phase 2: 10 balanced q-tile tasks: Q-proj (D->B-frag via
//             shfl_xor(32)), scores^T, lane-local softmax (exp2), PV with
//             register-built P-frags. Only 2 __syncthreads total.
//  proj:      Out = Attn @ Wout + bout. Attn bf16 lives IN d_out.

#define NN     320
#define DIMD   128
#define NHEADS 4
#define DH     64
#define INNERD 256
#define NPAIR  (NN*NN)
#define SCALE  0.125f
#define LOG2E  1.44269504f
#define SCL2   0.18033688f   // 0.125 * log2(e)

typedef __attribute__((ext_vector_type(8)))  short    bf16x8;
typedef __attribute__((ext_vector_type(16))) float    f32x16;
typedef __attribute__((ext_vector_type(4)))  unsigned u32x4;

#define MFMA32(a,b,c) __builtin_amdgcn_mfma_f32_32x32x16_bf16((a),(b),(c),0,0,0)

#if defined(__has_builtin)
# if __has_builtin(__builtin_amdgcn_exp2f)
#  define HAVE_EXP2 1
# endif
#endif

// pack two f32 -> 2x bf16 (RTNE), proven bit-math version
__device__ __forceinline__ unsigned pkbf(float lo, float hi){
  unsigned a = __builtin_bit_cast(unsigned, lo);
  unsigned b = __builtin_bit_cast(unsigned, hi);
  a = (a + 0x7fffu + ((a>>16)&1u)) >> 16;
  b = (b + 0x7fffu + ((b>>16)&1u)) >> 16;
  return (a & 0xffffu) | (b<<16);
}
__device__ __forceinline__ unsigned short bf1(float f){
  unsigned u = __builtin_bit_cast(unsigned, f);
  return (unsigned short)((u + 0x7fffu + ((u>>16)&1u)) >> 16);
}
__device__ __forceinline__ float ex2(float x){
#ifdef HAVE_EXP2
  return __builtin_amdgcn_exp2f(x);
#else
  return exp2f(x);
#endif
}
__device__ __forceinline__ f32x16 z16(){
  f32x16 v;
#pragma unroll
  for (int k = 0; k < 16; ++k) v[k] = 0.0f;
  return v;
}

// ---------------------------------------------------------------------------
// x2bf_bias: wave per pair p=(q,k). Read 128 fp32 (float2/lane), write 64 dwords
// bf16 (XBF), and 4-head bias dot via fp32 shfl-reduce into Bws[h][q][k].
// Bias pre-scaled by log2(e) so attn softmax can use exp2 directly.
// ---------------------------------------------------------------------------
template<bool XBF>
__global__ void __launch_bounds__(256) x2bf_bias(const float* __restrict__ X,
                                                 const float* __restrict__ Wbias,
                                                 float* __restrict__ Bws,
                                                 unsigned* __restrict__ XbfU){
  const int tid  = threadIdx.x;
  const int lane = tid & 63;
  const int p    = blockIdx.x*4 + (tid >> 6);
  const int q    = p / NN, k = p - q*NN;
  float2 v = ((const float2*)(X + (size_t)p*DIMD))[lane];
  float4 w0 = ((const float4*)Wbias)[2*lane];
  float4 w1 = ((const float4*)Wbias)[2*lane+1];
  float4 s;
  s.x = v.x*w0.x + v.y*w1.x;
  s.y = v.x*w0.y + v.y*w1.y;
  s.z = v.x*w0.z + v.y*w1.z;
  s.w = v.x*w0.w + v.y*w1.w;
  if (XBF) XbfU[(size_t)p*64 + lane] = pkbf(v.x, v.y);
#pragma unroll
  for (int off = 32; off >= 1; off >>= 1){
    s.x += __shfl_xor(s.x, off);
    s.y += __shfl_xor(s.y, off);
    s.z += __shfl_xor(s.z, off);
    s.w += __shfl_xor(s.w, off);
  }
  if (lane == 0){
    Bws[(size_t)0*NPAIR + q*NN + k] = s.x*LOG2E;
    Bws[(size_t)1*NPAIR + q*NN + k] = s.y*LOG2E;
    Bws[(size_t)2*NPAIR + q*NN + k] = s.z*LOG2E;
    Bws[(size_t)3*NPAIR + q*NN + k] = s.w*LOG2E;
  }
}

// ---------------------------------------------------------------------------
// wpack: Wqkvt[c*128+d] = bf16(Wqkv[d*768+c]).  Coalesced reads, tiny scatter.
// ---------------------------------------------------------------------------
__global__ void __launch_bounds__(256) wpack(const float* __restrict__ Wqkv,
                                             unsigned short* __restrict__ Wqkvt){
  const int idx = blockIdx.x*256 + threadIdx.x;   // < 98304
  const int c = idx % 768, d = idx / 768;
  Wqkvt[c*DIMD + d] = bf1(Wqkv[idx]);
}

// ---------------------------------------------------------------------------
// attn kernel.  LDS map (bytes):
//   K   [320 j][64 d]  stride 144 :      0 ..  46080
//   Vt  [64 d][320 j]  stride 656 :  46080 ..  88064
//   W   [192 col][128 din] str 272:  88064 .. 140288   (q:0-63, k:64-127, v:128-191)
// ---------------------------------------------------------------------------
#define KOFF   0
#define VTOFF  46080
#define WOFF   88064
#define LDS_A  140288
#define KSTR   144
#define VTSTR  656
#define WSTR   272
#define NTHR   640
#define NWAVE  10

template<bool XBF>
__device__ __forceinline__ bf16x8 xfrag(const float* Xf, const unsigned short* Xb,
                                        int row, int ks, int coff, int half){
  if constexpr (XBF){
    return *(const bf16x8*)((const char*)Xb + (size_t)row*256 + ks*32 + coff);
  } else {
    const float* p = Xf + (size_t)row*DIMD + ks*16 + half*8;
    float4 x0 = ((const float4*)p)[0], x1 = ((const float4*)p)[1];
    u32x4 v; v[0]=pkbf(x0.x,x0.y); v[1]=pkbf(x0.z,x0.w); v[2]=pkbf(x1.x,x1.y); v[3]=pkbf(x1.z,x1.w);
    return __builtin_bit_cast(bf16x8, v);
  }
}

template<bool XBF>
__global__ void __launch_bounds__(NTHR, 3) attn_kernel(const float* __restrict__ X,
                                                       const unsigned short* __restrict__ Xbf,
                                                       const float* __restrict__ Wqkv,
                                                       const unsigned short* __restrict__ Wqkvt,
                                                       const float* __restrict__ Bws,
                                                       unsigned short* __restrict__ AttnOut){
  extern __shared__ char sm[];
  const int h = blockIdx.x, i = blockIdx.y;
  const int tid  = threadIdx.x;
  const int w    = tid >> 6;          // 0..9
  const int lane = tid & 63;
  const int half = lane >> 5;
  const int l31  = lane & 31;
  const int coff = half*16;

  // ---- stage W (q|k|v cols for this head), transposed [col][din] bf16
  if (XBF){
    for (int idx = tid; idx < 192*16; idx += NTHR){
      const int col = idx >> 4, seg = idx & 15;
      const int gcol = (col < 64)  ? (h*DH + col)
                     : (col < 128) ? (INNERD   + h*DH + (col-64))
                                   : (2*INNERD + h*DH + (col-128));
      u32x4 v = *(const u32x4*)(Wqkvt + (size_t)gcol*DIMD + seg*8);
      *(u32x4*)(sm + WOFF + (size_t)col*WSTR + seg*16) = v;
    }
  } else if (tid < 192){
    const int col  = tid;
    const int gcol = (col < 64)  ? (h*DH + col)
                   : (col < 128) ? (INNERD   + h*DH + (col-64))
                                 : (2*INNERD + h*DH + (col-128));
    char* dst = sm + WOFF + (size_t)col*WSTR;
    for (int d0 = 0; d0 < DIMD; d0 += 8){
      u32x4 v;
      v[0] = pkbf(Wqkv[(size_t)(d0+0)*768 + gcol], Wqkv[(size_t)(d0+1)*768 + gcol]);
      v[1] = pkbf(Wqkv[(size_t)(d0+2)*768 + gcol], Wqkv[(size_t)(d0+3)*768 + gcol]);
      v[2] = pkbf(Wqkv[(size_t)(d0+4)*768 + gcol], Wqkv[(size_t)(d0+5)*768 + gcol]);
      v[3] = pkbf(Wqkv[(size_t)(d0+6)*768 + gcol], Wqkv[(size_t)(d0+7)*768 + gcol]);
      *(u32x4*)(dst + d0*2) = v;
    }
  }
  __syncthreads();

  // ============ phase 1: 20 balanced wave-tasks (10 K, 10 V), 2 per wave ======
#pragma unroll
  for (int r = 0; r < 2; ++r){
    const int t = w + NWAVE*r;          // 0..19 exactly
    const bool isK = (t < 10);
    const int  jt  = isK ? t : t - 10;
    const int  jrow = jt*32 + l31;
    const int  grow = i*NN + jrow;
    f32x16 acc0 = z16(), acc1 = z16();
    if (isK){
      const char* A0 = sm + WOFF + (size_t)(64 + l31)*WSTR;
      const char* A1 = sm + WOFF + (size_t)(96 + l31)*WSTR;
#pragma unroll
      for (int ks = 0; ks < 8; ++ks){
        bf16x8 b  = xfrag<XBF>(X, Xbf, grow, ks, coff, half);
        bf16x8 a0 = *(const bf16x8*)(A0 + ks*32 + coff);
        bf16x8 a1 = *(const bf16x8*)(A1 + ks*32 + coff);
        acc0 = MFMA32(a0, b, acc0);
        acc1 = MFMA32(a1, b, acc1);
      }
#pragma unroll
      for (int rq = 0; rq < 4; ++rq){
        uint2 v0, v1;
        v0.x = pkbf(acc0[4*rq+0], acc0[4*rq+1]); v0.y = pkbf(acc0[4*rq+2], acc0[4*rq+3]);
        v1.x = pkbf(acc1[4*rq+0], acc1[4*rq+1]); v1.y = pkbf(acc1[4*rq+2], acc1[4*rq+3]);
        *(uint2*)(sm + KOFF + (size_t)jrow*KSTR +      (8*rq + 4*half)*2) = v0;
        *(uint2*)(sm + KOFF + (size_t)jrow*KSTR + 64 + (8*rq + 4*half)*2) = v1;
      }
    } else {
      const char* B0 = sm + WOFF + (size_t)(128 + l31)*WSTR;
      const char* B1 = sm + WOFF + (size_t)(160 + l31)*WSTR;
#pragma unroll
      for (int ks = 0; ks < 8; ++ks){
        bf16x8 a  = xfrag<XBF>(X, Xbf, grow, ks, coff, half);
        bf16x8 b0 = *(const bf16x8*)(B0 + ks*32 + coff);
        bf16x8 b1 = *(const bf16x8*)(B1 + ks*32 + coff);
        acc0 = MFMA32(a, b0, acc0);
        acc1 = MFMA32(a, b1, acc1);
      }
#pragma unroll
      for (int rq = 0; rq < 4; ++rq){
        uint2 v0, v1;
        v0.x = pkbf(acc0[4*rq+0], acc0[4*rq+1]); v0.y = pkbf(acc0[4*rq+2], acc0[4*rq+3]);
        v1.x = pkbf(acc1[4*rq+0], acc1[4*rq+1]); v1.y = pkbf(acc1[4*rq+2], acc1[4*rq+3]);
        *(uint2*)(sm + VTOFF + (size_t)(     l31)*VTSTR + (jt*32 + 8*rq + 4*half)*2) = v0;
        *(uint2*)(sm + VTOFF + (size_t)(32 + l31)*VTSTR + (jt*32 + 8*rq + 4*half)*2) = v1;
      }
    }
  }
  __syncthreads();

  // ============ phase 2: 10 balanced q-tile wave-tasks, 1 per wave ============
  {
    const int qt = w;                   // 0..9
    const int q = qt*32 + l31;
    // ---- Q-proj: D col = q, rows = d
    f32x16 qa0 = z16(), qa1 = z16();
#pragma unroll
    for (int ks = 0; ks < 8; ++ks){
      bf16x8 b  = xfrag<XBF>(X, Xbf, i*NN + q, ks, coff, half);
      bf16x8 a0 = *(const bf16x8*)(sm + WOFF + (size_t)(     l31)*WSTR + ks*32 + coff);
      bf16x8 a1 = *(const bf16x8*)(sm + WOFF + (size_t)(32 + l31)*WSTR + ks*32 + coff);
      qa0 = MFMA32(a0, b, qa0);
      qa1 = MFMA32(a1, b, qa1);
    }
    // ---- build qf[4] (B-frags over d) in-register from D-layout via shfl_xor(32)
    bf16x8 qf[4];
    {
      unsigned a0 = pkbf(qa0[0],qa0[1]),  a0b = pkbf(qa0[2],qa0[3]);
      unsigned a1 = pkbf(qa0[4],qa0[5]),  a1b = pkbf(qa0[6],qa0[7]);
      unsigned a2 = pkbf(qa0[8],qa0[9]),  a2b = pkbf(qa0[10],qa0[11]);
      unsigned a3 = pkbf(qa0[12],qa0[13]),a3b = pkbf(qa0[14],qa0[15]);
      unsigned b0 = pkbf(qa1[0],qa1[1]),  b0b = pkbf(qa1[2],qa1[3]);
      unsigned b1 = pkbf(qa1[4],qa1[5]),  b1b = pkbf(qa1[6],qa1[7]);
      unsigned b2 = pkbf(qa1[8],qa1[9]),  b2b = pkbf(qa1[10],qa1[11]);
      unsigned b3 = pkbf(qa1[12],qa1[13]),b3b = pkbf(qa1[14],qa1[15]);
      unsigned sa0=__shfl_xor(a0,32), sa0b=__shfl_xor(a0b,32);
      unsigned sa1=__shfl_xor(a1,32), sa1b=__shfl_xor(a1b,32);
      unsigned sa2=__shfl_xor(a2,32), sa2b=__shfl_xor(a2b,32);
      unsigned sa3=__shfl_xor(a3,32), sa3b=__shfl_xor(a3b,32);
      unsigned sb0=__shfl_xor(b0,32), sb0b=__shfl_xor(b0b,32);
      unsigned sb1=__shfl_xor(b1,32), sb1b=__shfl_xor(b1b,32);
      unsigned sb2=__shfl_xor(b2,32), sb2b=__shfl_xor(b2b,32);
      unsigned sb3=__shfl_xor(b3,32), sb3b=__shfl_xor(b3b,32);
      u32x4 f;
      if (half == 0){
        f[0]=a0; f[1]=a0b; f[2]=sa0; f[3]=sa0b; qf[0]=__builtin_bit_cast(bf16x8,f);
        f[0]=a2; f[1]=a2b; f[2]=sa2; f[3]=sa2b; qf[1]=__builtin_bit_cast(bf16x8,f);
        f[0]=b0; f[1]=b0b; f[2]=sb0; f[3]=sb0b; qf[2]=__builtin_bit_cast(bf16x8,f);
        f[0]=b2; f[1]=b2b; f[2]=sb2; f[3]=sb2b; qf[3]=__builtin_bit_cast(bf16x8,f);
      } else {
        f[0]=sa1; f[1]=sa1b; f[2]=a1; f[3]=a1b; qf[0]=__builtin_bit_cast(bf16x8,f);
        f[0]=sa3; f[1]=sa3b; f[2]=a3; f[3]=a3b; qf[1]=__builtin_bit_cast(bf16x8,f);
        f[0]=sb1; f[1]=sb1b; f[2]=b1; f[3]=b1b; qf[2]=__builtin_bit_cast(bf16x8,f);
        f[0]=sb3; f[1]=sb3b; f[2]=b3; f[3]=b3b; qf[3]=__builtin_bit_cast(bf16x8,f);
      }
    }
    // ---- scores^T: S[j][q], D col = q = l31, rows = j
    f32x16 S[10];
#pragma unroll
    for (int jt = 0; jt < 10; ++jt) S[jt] = z16();
#pragma unroll
    for (int jt = 0; jt < 10; ++jt){
#pragma unroll
      for (int c = 0; c < 4; ++c){
        bf16x8 a = *(const bf16x8*)(sm + KOFF + (size_t)(jt*32 + l31)*KSTR + c*32 + coff);
        S[jt] = MFMA32(a, qf[c], S[jt]);
      }
    }
    // ---- scale + bias in exp2 domain (float4 per rq) + softmax over j
    const float4* Bf = (const float4*)(Bws + (size_t)h*NPAIR + (size_t)q*NN);
    float m = -3.0e38f;
#pragma unroll
    for (int jt = 0; jt < 10; ++jt){
#pragma unroll
      for (int rq = 0; rq < 4; ++rq){
        float4 bv = Bf[jt*8 + 2*rq + half];
        float v0 = S[jt][4*rq+0]*SCL2 + bv.x;
        float v1 = S[jt][4*rq+1]*SCL2 + bv.y;
        float v2 = S[jt][4*rq+2]*SCL2 + bv.z;
        float v3 = S[jt][4*rq+3]*SCL2 + bv.w;
        S[jt][4*rq+0]=v0; S[jt][4*rq+1]=v1; S[jt][4*rq+2]=v2; S[jt][4*rq+3]=v3;
        m = fmaxf(m, fmaxf(fmaxf(v0,v1), fmaxf(v2,v3)));
      }
    }
    m = fmaxf(m, __shfl_xor(m, 32));
    float l = 0.0f;
#pragma unroll
    for (int jt = 0; jt < 10; ++jt){
#pragma unroll
      for (int k = 0; k < 16; ++k){
        float e = ex2(S[jt][k] - m);
        S[jt][k] = e;
        l += e;
      }
    }
    l += __shfl_xor(l, 32);
    const float rl = 1.0f / l;
    // ---- PV: O^T[d][q] += Vt[d][j] * P^T[j][q]; P-frags from S regs via shfl.
    f32x16 o0 = z16(), o1 = z16();
#pragma unroll
    for (int jt = 0; jt < 10; ++jt){
      unsigned P0a = pkbf(S[jt][0], S[jt][1]),  P0b = pkbf(S[jt][2], S[jt][3]);
      unsigned P1a = pkbf(S[jt][4], S[jt][5]),  P1b = pkbf(S[jt][6], S[jt][7]);
      unsigned P2a = pkbf(S[jt][8], S[jt][9]),  P2b = pkbf(S[jt][10],S[jt][11]);
      unsigned P3a = pkbf(S[jt][12],S[jt][13]), P3b = pkbf(S[jt][14],S[jt][15]);
      unsigned s0a = __shfl_xor(P0a,32), s0b = __shfl_xor(P0b,32);
      unsigned s1a = __shfl_xor(P1a,32), s1b = __shfl_xor(P1b,32);
      unsigned s2a = __shfl_xor(P2a,32), s2b = __shfl_xor(P2b,32);
      unsigned s3a = __shfl_xor(P3a,32), s3b = __shfl_xor(P3b,32);
      u32x4 fe, fo;
      if (half == 0){ fe[0]=P0a; fe[1]=P0b; fe[2]=s0a; fe[3]=s0b;
                      fo[0]=P2a; fo[1]=P2b; fo[2]=s2a; fo[3]=s2b; }
      else          { fe[0]=s1a; fe[1]=s1b; fe[2]=P1a; fe[3]=P1b;
                      fo[0]=s3a; fo[1]=s3b; fo[2]=P3a; fo[3]=P3b; }
      bf16x8 pe = __builtin_bit_cast(bf16x8, fe);
      bf16x8 po = __builtin_bit_cast(bf16x8, fo);
      bf16x8 va0e = *(const bf16x8*)(sm + VTOFF + (size_t)(     l31)*VTSTR + jt*64 + coff);
      bf16x8 va1e = *(const bf16x8*)(sm + VTOFF + (size_t)(32 + l31)*VTSTR + jt*64 + coff);
      bf16x8 va0o = *(const bf16x8*)(sm + VTOFF + (size_t)(     l31)*VTSTR + jt*64 + 32 + coff);
      bf16x8 va1o = *(const bf16x8*)(sm + VTOFF + (size_t)(32 + l31)*VTSTR + jt*64 + 32 + coff);
      o0 = MFMA32(va0e, pe, o0);
      o1 = MFMA32(va1e, pe, o1);
      o0 = MFMA32(va0o, po, o0);
      o1 = MFMA32(va1o, po, o1);
    }
    // ---- epilogue
    const size_t rowbase = (((size_t)i*NN) + q)*INNERD + h*DH;
#pragma unroll
    for (int rq = 0; rq < 4; ++rq){
      const int dd = 8*rq + 4*half;
      uint2 v0, v1;
      v0.x = pkbf(o0[4*rq+0]*rl, o0[4*rq+1]*rl); v0.y = pkbf(o0[4*rq+2]*rl, o0[4*rq+3]*rl);
      v1.x = pkbf(o1[4*rq+0]*rl, o1[4*rq+1]*rl); v1.y = pkbf(o1[4*rq+2]*rl, o1[4*rq+3]*rl);
      *(uint2*)(AttnOut + rowbase + dd)      = v0;
      *(uint2*)(AttnOut + rowbase + 32 + dd) = v1;
    }
  }
}

// ---------------------------------------------------------------------------
// proj: Out = Attn @ Wout + bout.  LDS = W^T only (67.6 KB -> 2 WG/CU).
// A-frags straight from global; wave reads exactly the 32 rows it later writes
// (program-order read-before-write => alias-safe with Attn in d_out).
// ---------------------------------------------------------------------------
#define B_WSTR 528
#define LDS_P  67584

__global__ void __launch_bounds__(256, 2) proj_kernel(const unsigned short* Attn,
                                                      const float* __restrict__ Wout,
                                                      const float* __restrict__ bout,
                                                      float* Out){
  extern __shared__ char sm[];
  const int tid = threadIdx.x, w = tid>>6, lane = tid&63, half = lane>>5, l31 = lane&31;
  const int coff = half*16;
  const size_t r0 = (size_t)blockIdx.x * 128;
  if (tid < 128){                            // stage Wout^T [col][din] bf16
    const int col = tid;
    char* dst = sm + (size_t)col*B_WSTR;
    for (int d0 = 0; d0 < 256; d0 += 8){
      u32x4 v;
      v[0] = pkbf(Wout[(size_t)(d0+0)*DIMD + col], Wout[(size_t)(d0+1)*DIMD + col]);
      v[1] = pkbf(Wout[(size_t)(d0+2)*DIMD + col], Wout[(size_t)(d0+3)*DIMD + col]);
      v[2] = pkbf(Wout[(size_t)(d0+4)*DIMD + col], Wout[(size_t)(d0+5)*DIMD + col]);
      v[3] = pkbf(Wout[(size_t)(d0+6)*DIMD + col], Wout[(size_t)(d0+7)*DIMD + col]);
      *(u32x4*)(dst + d0*2) = v;
    }
  }
  __syncthreads();
  f32x16 acc[4];
#pragma unroll
  for (int nt = 0; nt < 4; ++nt){
    float bv = bout[nt*32 + l31];
#pragma unroll
    for (int k = 0; k < 16; ++k) acc[nt][k] = bv;
  }
  const char* Ab = (const char*)Attn + (r0 + w*32 + l31)*512;
#pragma unroll
  for (int ks = 0; ks < 16; ++ks){
    bf16x8 a = *(const bf16x8*)(Ab + ks*32 + coff);
#pragma unroll
    for (int nt = 0; nt < 4; ++nt){
      bf16x8 b = *(const bf16x8*)(sm + (size_t)(nt*32 + l31)*B_WSTR + ks*32 + coff);
      acc[nt] = MFMA32(a, b, acc[nt]);
    }
  }
#pragma unroll
  for (int nt = 0; nt < 4; ++nt){
    const int c = nt*32 + l31;
#pragma unroll
    for (int rq = 0; rq < 4; ++rq){
#pragma unroll
      for (int r = 0; r < 4; ++r){
        const int rr = w*32 + 8*rq + 4*half + r;
        Out[(r0 + rr)*DIMD + c] = acc[nt][4*rq + r];
      }
    }
  }
}

// ---------------------------------------------------------------------------
extern "C" void kernel_launch(void* const* d_in, const int* in_sizes, int n_in,
                              void* d_out, int out_size, void* d_ws, size_t ws_size,
                              hipStream_t stream){
  const float* X     = (const float*)d_in[0];
  const float* Wqkv  = (const float*)d_in[1];
  const float* Wout  = (const float*)d_in[2];
  const float* bout  = (const float*)d_in[3];
  const float* Wbias = (const float*)d_in[4];
  float* Out = (float*)d_out;

  // ws layout: Bws fp32 [0,1638400) | Xbf bf16 [1638400,27852800) | Wqkvt [.., 28049408)
  float*          Bws   = (float*)d_ws;
  unsigned short* Xbf   = (unsigned short*)((char*)d_ws + 1638400);
  unsigned*       XbfU  = (unsigned*)Xbf;
  unsigned short* Wqkvt = (unsigned short*)((char*)d_ws + 27852800);
  const bool use_bf = (ws_size >= (size_t)28049408);

  unsigned short* Attn = (unsigned short*)d_out;   // bf16 intermediate lives in d_out

  (void)hipFuncSetAttribute((const void*)proj_kernel,
                            hipFuncAttributeMaxDynamicSharedMemorySize, LDS_P);
  if (use_bf){
    (void)hipFuncSetAttribute((const void*)attn_kernel<true>,
                              hipFuncAttributeMaxDynamicSharedMemorySize, LDS_A);
    x2bf_bias<true><<<NPAIR/4, 256, 0, stream>>>(X, Wbias, Bws, XbfU);
    wpack<<<768*DIMD/256, 256, 0, stream>>>(Wqkv, Wqkvt);
    attn_kernel<true><<<dim3(NHEADS, NN), NTHR, LDS_A, stream>>>(X, Xbf, Wqkv, Wqkvt, Bws, Attn);
  } else {
    (void)hipFuncSetAttribute((const void*)attn_kernel<false>,
                              hipFuncAttributeMaxDynamicSharedMemorySize, LDS_A);
    x2bf_bias<false><<<NPAIR/4, 256, 0, stream>>>(X, Wbias, Bws, nullptr);
    attn_kernel<false><<<dim3(NHEADS, NN), NTHR, LDS_A, stream>>>(X, nullptr, Wqkv, nullptr, Bws, Attn);
  }
  proj_kernel<<<NPAIR/128, 256, LDS_P, stream>>>(Attn, Wout, bout, Out);
}

// Round 6
// 346.951 us; speedup vs baseline: 1.1474x; 1.1469x over previous
//
#include <hip/hip_runtime.h>

// TriangleAttention (starting node), MI355X gfx950.  Round 7.
// B=1, N=320, DIM=128, HEADS=4, DH=64, INNER=256. fp32 I/O, bf16 MFMA inside.
//
// Round-7: 640-thr geometry abandoned (10-wave WG caps regs at ~170 total ->
// softmax state can't fit arch VGPRs -> unavoidable spill; r5/r6 evidence).
// New geometry: 256 thr / 4 waves per block, LDS cut to EXACTLY 80 KiB so
// TWO blocks co-reside per CU (2x81920 = 163840 = full LDS):
//  * W LDS stage dropped -> Wqkvt read straight from L2 (196 KB, L2-resident).
//  * K [320][128B] and Vt [64][640B] stored swizzled: cb ^= (row&7)<<4
//    (replaces pad; same 4-way conflict class as old padded strides).
//  * phase-1: 20 tasks / 4 waves = 5 rounds (100% eff);
//    phase-2: 10 tasks / 4 waves = 3 rounds (83% vs old 62.5%).
//  * 2 desynced blocks/CU overlap VALU-heavy phase-2 with load/MFMA phase-1.
//  * softmax sum/max chains tree-ified; exp2-domain (verified r5);
//    bit-math pkbf (cvt_pk asm NaN'd r3/r4 -> banned); s_setprio on MFMA.
//
// Pipeline:
//  x2bf_bias: wave per (q,k): X fp32 -> Xbf bf16 (ws) + bias GEMV*log2e -> Bws.
//  wpack:     Wqkv fp32 -> Wqkvt bf16 [col 768][din 128] (ws).
//  attn:      per (h,i), 256 thr / 4 waves, LDS 80 KiB, ONE __syncthreads.
//  proj:      Out = Attn @ Wout + bout. Attn bf16 lives IN d_out.

#define NN     320
#define DIMD   128
#define NHEADS 4
#define DH     64
#define INNERD 256
#define NPAIR  (NN*NN)
#define LOG2E  1.44269504f
#define SCL2   0.18033688f   // 0.125 * log2(e)

typedef __attribute__((ext_vector_type(8)))  short    bf16x8;
typedef __attribute__((ext_vector_type(16))) float    f32x16;
typedef __attribute__((ext_vector_type(4)))  unsigned u32x4;

#define MFMA32(a,b,c) __builtin_amdgcn_mfma_f32_32x32x16_bf16((a),(b),(c),0,0,0)

#if defined(__has_builtin)
# if __has_builtin(__builtin_amdgcn_exp2f)
#  define HAVE_EXP2 1
# endif
#endif

// pack two f32 -> 2x bf16 (RTNE), proven bit-math version
__device__ __forceinline__ unsigned pkbf(float lo, float hi){
  unsigned a = __builtin_bit_cast(unsigned, lo);
  unsigned b = __builtin_bit_cast(unsigned, hi);
  a = (a + 0x7fffu + ((a>>16)&1u)) >> 16;
  b = (b + 0x7fffu + ((b>>16)&1u)) >> 16;
  return (a & 0xffffu) | (b<<16);
}
__device__ __forceinline__ unsigned short bf1(float f){
  unsigned u = __builtin_bit_cast(unsigned, f);
  return (unsigned short)((u + 0x7fffu + ((u>>16)&1u)) >> 16);
}
__device__ __forceinline__ float ex2(float x){
#ifdef HAVE_EXP2
  return __builtin_amdgcn_exp2f(x);
#else
  return exp2f(x);
#endif
}
__device__ __forceinline__ f32x16 z16(){
  f32x16 v;
#pragma unroll
  for (int k = 0; k < 16; ++k) v[k] = 0.0f;
  return v;
}

// ---------------------------------------------------------------------------
// x2bf_bias: wave per pair p=(q,k). Read 128 fp32 (float2/lane), write 64 dwords
// bf16 (XBF), and 4-head bias dot via fp32 shfl-reduce into Bws[h][q][k].
// Bias pre-scaled by log2(e) so attn softmax can use exp2 directly.
// ---------------------------------------------------------------------------
template<bool XBF>
__global__ void __launch_bounds__(256) x2bf_bias(const float* __restrict__ X,
                                                 const float* __restrict__ Wbias,
                                                 float* __restrict__ Bws,
                                                 unsigned* __restrict__ XbfU){
  const int tid  = threadIdx.x;
  const int lane = tid & 63;
  const int p    = blockIdx.x*4 + (tid >> 6);
  const int q    = p / NN, k = p - q*NN;
  float2 v = ((const float2*)(X + (size_t)p*DIMD))[lane];
  float4 w0 = ((const float4*)Wbias)[2*lane];
  float4 w1 = ((const float4*)Wbias)[2*lane+1];
  float4 s;
  s.x = v.x*w0.x + v.y*w1.x;
  s.y = v.x*w0.y + v.y*w1.y;
  s.z = v.x*w0.z + v.y*w1.z;
  s.w = v.x*w0.w + v.y*w1.w;
  if (XBF) XbfU[(size_t)p*64 + lane] = pkbf(v.x, v.y);
#pragma unroll
  for (int off = 32; off >= 1; off >>= 1){
    s.x += __shfl_xor(s.x, off);
    s.y += __shfl_xor(s.y, off);
    s.z += __shfl_xor(s.z, off);
    s.w += __shfl_xor(s.w, off);
  }
  if (lane == 0){
    Bws[(size_t)0*NPAIR + q*NN + k] = s.x*LOG2E;
    Bws[(size_t)1*NPAIR + q*NN + k] = s.y*LOG2E;
    Bws[(size_t)2*NPAIR + q*NN + k] = s.z*LOG2E;
    Bws[(size_t)3*NPAIR + q*NN + k] = s.w*LOG2E;
  }
}

// ---------------------------------------------------------------------------
// wpack: Wqkvt[c*128+d] = bf16(Wqkv[d*768+c]).  Coalesced reads, tiny scatter.
// ---------------------------------------------------------------------------
__global__ void __launch_bounds__(256) wpack(const float* __restrict__ Wqkv,
                                             unsigned short* __restrict__ Wqkvt){
  const int idx = blockIdx.x*256 + threadIdx.x;   // < 98304
  const int c = idx % 768, d = idx / 768;
  Wqkvt[c*DIMD + d] = bf1(Wqkv[idx]);
}

// ---------------------------------------------------------------------------
// attn kernel.  LDS map (bytes), both regions XOR-swizzled (cb ^= (row&7)<<4):
//   K   [320 row][128 B]  :     0 .. 40960
//   Vt  [ 64 row][640 B]  : 40960 .. 81920   (exactly 80 KiB -> 2 blocks/CU)
// ---------------------------------------------------------------------------
#define KOFF   0
#define VTOFF  40960
#define LDS_A  81920
#define NTHR   256
#define NWAVE  4

__device__ __forceinline__ char* kptr(char* sm, int row, int cb){
  return sm + KOFF + row*128 + (cb ^ ((row & 7) << 4));
}
__device__ __forceinline__ char* vptr(char* sm, int row, int cb){
  return sm + VTOFF + row*640 + (cb ^ ((row & 7) << 4));
}

template<bool XBF>
__device__ __forceinline__ bf16x8 xfrag(const float* Xf, const unsigned short* Xb,
                                        int row, int ks, int coff, int half){
  if constexpr (XBF){
    return *(const bf16x8*)((const char*)Xb + (size_t)row*256 + ks*32 + coff);
  } else {
    const float* p = Xf + (size_t)row*DIMD + ks*16 + half*8;
    float4 x0 = ((const float4*)p)[0], x1 = ((const float4*)p)[1];
    u32x4 v; v[0]=pkbf(x0.x,x0.y); v[1]=pkbf(x0.z,x0.w); v[2]=pkbf(x1.x,x1.y); v[3]=pkbf(x1.z,x1.w);
    return __builtin_bit_cast(bf16x8, v);
  }
}

// W fragment straight from global (L2-resident Wqkvt; slow fp32 fallback).
template<bool XBF>
__device__ __forceinline__ bf16x8 wfrag(const unsigned short* Wt, const float* Wq,
                                        int gcol, int ks, int half){
  if constexpr (XBF){
    return *(const bf16x8*)(Wt + (size_t)gcol*DIMD + ks*16 + 8*half);
  } else {
    const int d0 = ks*16 + 8*half;
    u32x4 v;
    v[0] = pkbf(Wq[(size_t)(d0+0)*768 + gcol], Wq[(size_t)(d0+1)*768 + gcol]);
    v[1] = pkbf(Wq[(size_t)(d0+2)*768 + gcol], Wq[(size_t)(d0+3)*768 + gcol]);
    v[2] = pkbf(Wq[(size_t)(d0+4)*768 + gcol], Wq[(size_t)(d0+5)*768 + gcol]);
    v[3] = pkbf(Wq[(size_t)(d0+6)*768 + gcol], Wq[(size_t)(d0+7)*768 + gcol]);
    return __builtin_bit_cast(bf16x8, v);
  }
}

template<bool XBF>
__global__ void __launch_bounds__(NTHR, 2) attn_kernel(const float* __restrict__ X,
                                                       const unsigned short* __restrict__ Xbf,
                                                       const float* __restrict__ Wqkv,
                                                       const unsigned short* __restrict__ Wqkvt,
                                                       const float* __restrict__ Bws,
                                                       unsigned short* __restrict__ AttnOut){
  extern __shared__ char sm[];
  const int h = blockIdx.x, i = blockIdx.y;
  const int tid  = threadIdx.x;
  const int w    = tid >> 6;          // 0..3
  const int lane = tid & 63;
  const int half = lane >> 5;
  const int l31  = lane & 31;
  const int coff = half*16;

  // ============ phase 1: 20 wave-tasks (10 K, 10 V), 5 per wave, no stage ====
#pragma unroll
  for (int r = 0; r < 5; ++r){
    const int t = w + NWAVE*r;          // 0..19 exactly
    const bool isK = (t < 10);
    const int  jt  = isK ? t : t - 10;
    const int  jrow = jt*32 + l31;
    const int  grow = i*NN + jrow;
    f32x16 acc0 = z16(), acc1 = z16();
    if (isK){
      const int g0 = INNERD   + h*DH + l31;        // k-cols
      const int g1 = INNERD   + h*DH + 32 + l31;
#pragma unroll
      for (int ks = 0; ks < 8; ++ks){
        bf16x8 b  = xfrag<XBF>(X, Xbf, grow, ks, coff, half);
        bf16x8 a0 = wfrag<XBF>(Wqkvt, Wqkv, g0, ks, half);
        bf16x8 a1 = wfrag<XBF>(Wqkvt, Wqkv, g1, ks, half);
        acc0 = MFMA32(a0, b, acc0);
        acc1 = MFMA32(a1, b, acc1);
      }
#pragma unroll
      for (int rq = 0; rq < 4; ++rq){
        uint2 v0, v1;
        v0.x = pkbf(acc0[4*rq+0], acc0[4*rq+1]); v0.y = pkbf(acc0[4*rq+2], acc0[4*rq+3]);
        v1.x = pkbf(acc1[4*rq+0], acc1[4*rq+1]); v1.y = pkbf(acc1[4*rq+2], acc1[4*rq+3]);
        const int cb0 = (8*rq + 4*half)*2;
        *(uint2*)kptr(sm, jrow, cb0)      = v0;
        *(uint2*)kptr(sm, jrow, 64 + cb0) = v1;
      }
    } else {
      const int g0 = 2*INNERD + h*DH + l31;        // v-cols
      const int g1 = 2*INNERD + h*DH + 32 + l31;
#pragma unroll
      for (int ks = 0; ks < 8; ++ks){
        bf16x8 a  = xfrag<XBF>(X, Xbf, grow, ks, coff, half);
        bf16x8 b0 = wfrag<XBF>(Wqkvt, Wqkv, g0, ks, half);
        bf16x8 b1 = wfrag<XBF>(Wqkvt, Wqkv, g1, ks, half);
        acc0 = MFMA32(a, b0, acc0);
        acc1 = MFMA32(a, b1, acc1);
      }
#pragma unroll
      for (int rq = 0; rq < 4; ++rq){
        uint2 v0, v1;
        v0.x = pkbf(acc0[4*rq+0], acc0[4*rq+1]); v0.y = pkbf(acc0[4*rq+2], acc0[4*rq+3]);
        v1.x = pkbf(acc1[4*rq+0], acc1[4*rq+1]); v1.y = pkbf(acc1[4*rq+2], acc1[4*rq+3]);
        const int cb = (jt*32 + 8*rq + 4*half)*2;
        *(uint2*)vptr(sm,      l31, cb) = v0;
        *(uint2*)vptr(sm, 32 + l31, cb) = v1;
      }
    }
  }
  __syncthreads();

  // ============ phase 2: 10 q-tile wave-tasks, 3 rounds over 4 waves =========
#pragma unroll
  for (int rep = 0; rep < 3; ++rep){
    const int qt = w + NWAVE*rep;
    if (qt >= 10) continue;
    const int q = qt*32 + l31;
    // ---- Q-proj: D col = q, rows = d (W q-cols straight from L2)
    f32x16 qa0 = z16(), qa1 = z16();
    {
      const int g0 = h*DH + l31;
      const int g1 = h*DH + 32 + l31;
#pragma unroll
      for (int ks = 0; ks < 8; ++ks){
        bf16x8 b  = xfrag<XBF>(X, Xbf, i*NN + q, ks, coff, half);
        bf16x8 a0 = wfrag<XBF>(Wqkvt, Wqkv, g0, ks, half);
        bf16x8 a1 = wfrag<XBF>(Wqkvt, Wqkv, g1, ks, half);
        qa0 = MFMA32(a0, b, qa0);
        qa1 = MFMA32(a1, b, qa1);
      }
    }
    // ---- build qf[4] (B-frags over d) in-register from D-layout via shfl_xor(32)
    bf16x8 qf[4];
    {
      unsigned a0 = pkbf(qa0[0],qa0[1]),  a0b = pkbf(qa0[2],qa0[3]);
      unsigned a1 = pkbf(qa0[4],qa0[5]),  a1b = pkbf(qa0[6],qa0[7]);
      unsigned a2 = pkbf(qa0[8],qa0[9]),  a2b = pkbf(qa0[10],qa0[11]);
      unsigned a3 = pkbf(qa0[12],qa0[13]),a3b = pkbf(qa0[14],qa0[15]);
      unsigned b0 = pkbf(qa1[0],qa1[1]),  b0b = pkbf(qa1[2],qa1[3]);
      unsigned b1 = pkbf(qa1[4],qa1[5]),  b1b = pkbf(qa1[6],qa1[7]);
      unsigned b2 = pkbf(qa1[8],qa1[9]),  b2b = pkbf(qa1[10],qa1[11]);
      unsigned b3 = pkbf(qa1[12],qa1[13]),b3b = pkbf(qa1[14],qa1[15]);
      unsigned sa0=__shfl_xor(a0,32), sa0b=__shfl_xor(a0b,32);
      unsigned sa1=__shfl_xor(a1,32), sa1b=__shfl_xor(a1b,32);
      unsigned sa2=__shfl_xor(a2,32), sa2b=__shfl_xor(a2b,32);
      unsigned sa3=__shfl_xor(a3,32), sa3b=__shfl_xor(a3b,32);
      unsigned sb0=__shfl_xor(b0,32), sb0b=__shfl_xor(b0b,32);
      unsigned sb1=__shfl_xor(b1,32), sb1b=__shfl_xor(b1b,32);
      unsigned sb2=__shfl_xor(b2,32), sb2b=__shfl_xor(b2b,32);
      unsigned sb3=__shfl_xor(b3,32), sb3b=__shfl_xor(b3b,32);
      u32x4 f;
      if (half == 0){
        f[0]=a0; f[1]=a0b; f[2]=sa0; f[3]=sa0b; qf[0]=__builtin_bit_cast(bf16x8,f);
        f[0]=a2; f[1]=a2b; f[2]=sa2; f[3]=sa2b; qf[1]=__builtin_bit_cast(bf16x8,f);
        f[0]=b0; f[1]=b0b; f[2]=sb0; f[3]=sb0b; qf[2]=__builtin_bit_cast(bf16x8,f);
        f[0]=b2; f[1]=b2b; f[2]=sb2; f[3]=sb2b; qf[3]=__builtin_bit_cast(bf16x8,f);
      } else {
        f[0]=sa1; f[1]=sa1b; f[2]=a1; f[3]=a1b; qf[0]=__builtin_bit_cast(bf16x8,f);
        f[0]=sa3; f[1]=sa3b; f[2]=a3; f[3]=a3b; qf[1]=__builtin_bit_cast(bf16x8,f);
        f[0]=sb1; f[1]=sb1b; f[2]=b1; f[3]=b1b; qf[2]=__builtin_bit_cast(bf16x8,f);
        f[0]=sb3; f[1]=sb3b; f[2]=b3; f[3]=b3b; qf[3]=__builtin_bit_cast(bf16x8,f);
      }
    }
    // ---- scores^T: S[j][q], D col = q = l31, rows = j
    f32x16 S[10];
#pragma unroll
    for (int jt = 0; jt < 10; ++jt) S[jt] = z16();
    __builtin_amdgcn_s_setprio(1);
#pragma unroll
    for (int jt = 0; jt < 10; ++jt){
#pragma unroll
      for (int c = 0; c < 4; ++c){
        bf16x8 a = *(const bf16x8*)kptr(sm, jt*32 + l31, c*32 + coff);
        S[jt] = MFMA32(a, qf[c], S[jt]);
      }
    }
    __builtin_amdgcn_s_setprio(0);
    // ---- scale + bias in exp2 domain + softmax over j (tree-reduced chains)
    const float4* Bf = (const float4*)(Bws + (size_t)h*NPAIR + (size_t)q*NN);
    float m = -3.0e38f;
#pragma unroll
    for (int jt = 0; jt < 10; ++jt){
      float mj = -3.0e38f;
#pragma unroll
      for (int rq = 0; rq < 4; ++rq){
        float4 bv = Bf[jt*8 + 2*rq + half];
        float v0 = S[jt][4*rq+0]*SCL2 + bv.x;
        float v1 = S[jt][4*rq+1]*SCL2 + bv.y;
        float v2 = S[jt][4*rq+2]*SCL2 + bv.z;
        float v3 = S[jt][4*rq+3]*SCL2 + bv.w;
        S[jt][4*rq+0]=v0; S[jt][4*rq+1]=v1; S[jt][4*rq+2]=v2; S[jt][4*rq+3]=v3;
        mj = fmaxf(mj, fmaxf(fmaxf(v0,v1), fmaxf(v2,v3)));
      }
      m = fmaxf(m, mj);
    }
    m = fmaxf(m, __shfl_xor(m, 32));
    float l = 0.0f;
#pragma unroll
    for (int jt = 0; jt < 10; ++jt){
      float t0 = 0.f, t1 = 0.f, t2 = 0.f, t3 = 0.f;
#pragma unroll
      for (int k = 0; k < 4; ++k){
        float e0 = ex2(S[jt][4*k+0] - m);
        float e1 = ex2(S[jt][4*k+1] - m);
        float e2 = ex2(S[jt][4*k+2] - m);
        float e3 = ex2(S[jt][4*k+3] - m);
        S[jt][4*k+0]=e0; S[jt][4*k+1]=e1; S[jt][4*k+2]=e2; S[jt][4*k+3]=e3;
        t0 += e0; t1 += e1; t2 += e2; t3 += e3;
      }
      l += (t0 + t1) + (t2 + t3);
    }
    l += __shfl_xor(l, 32);
    const float rl = 1.0f / l;
    // ---- PV: O^T[d][q] += Vt[d][j] * P^T[j][q]; P-frags from S regs via shfl.
    f32x16 o0 = z16(), o1 = z16();
#pragma unroll
    for (int jt = 0; jt < 10; ++jt){
      unsigned P0a = pkbf(S[jt][0], S[jt][1]),  P0b = pkbf(S[jt][2], S[jt][3]);
      unsigned P1a = pkbf(S[jt][4], S[jt][5]),  P1b = pkbf(S[jt][6], S[jt][7]);
      unsigned P2a = pkbf(S[jt][8], S[jt][9]),  P2b = pkbf(S[jt][10],S[jt][11]);
      unsigned P3a = pkbf(S[jt][12],S[jt][13]), P3b = pkbf(S[jt][14],S[jt][15]);
      unsigned s0a = __shfl_xor(P0a,32), s0b = __shfl_xor(P0b,32);
      unsigned s1a = __shfl_xor(P1a,32), s1b = __shfl_xor(P1b,32);
      unsigned s2a = __shfl_xor(P2a,32), s2b = __shfl_xor(P2b,32);
      unsigned s3a = __shfl_xor(P3a,32), s3b = __shfl_xor(P3b,32);
      u32x4 fe, fo;
      if (half == 0){ fe[0]=P0a; fe[1]=P0b; fe[2]=s0a; fe[3]=s0b;
                      fo[0]=P2a; fo[1]=P2b; fo[2]=s2a; fo[3]=s2b; }
      else          { fe[0]=s1a; fe[1]=s1b; fe[2]=P1a; fe[3]=P1b;
                      fo[0]=s3a; fo[1]=s3b; fo[2]=P3a; fo[3]=P3b; }
      bf16x8 pe = __builtin_bit_cast(bf16x8, fe);
      bf16x8 po = __builtin_bit_cast(bf16x8, fo);
      bf16x8 va0e = *(const bf16x8*)vptr(sm,      l31, jt*64 + coff);
      bf16x8 va1e = *(const bf16x8*)vptr(sm, 32 + l31, jt*64 + coff);
      bf16x8 va0o = *(const bf16x8*)vptr(sm,      l31, jt*64 + 32 + coff);
      bf16x8 va1o = *(const bf16x8*)vptr(sm, 32 + l31, jt*64 + 32 + coff);
      __builtin_amdgcn_s_setprio(1);
      o0 = MFMA32(va0e, pe, o0);
      o1 = MFMA32(va1e, pe, o1);
      o0 = MFMA32(va0o, po, o0);
      o1 = MFMA32(va1o, po, o1);
      __builtin_amdgcn_s_setprio(0);
    }
    // ---- epilogue
    const size_t rowbase = (((size_t)i*NN) + q)*INNERD + h*DH;
#pragma unroll
    for (int rq = 0; rq < 4; ++rq){
      const int dd = 8*rq + 4*half;
      uint2 v0, v1;
      v0.x = pkbf(o0[4*rq+0]*rl, o0[4*rq+1]*rl); v0.y = pkbf(o0[4*rq+2]*rl, o0[4*rq+3]*rl);
      v1.x = pkbf(o1[4*rq+0]*rl, o1[4*rq+1]*rl); v1.y = pkbf(o1[4*rq+2]*rl, o1[4*rq+3]*rl);
      *(uint2*)(AttnOut + rowbase + dd)      = v0;
      *(uint2*)(AttnOut + rowbase + 32 + dd) = v1;
    }
  }
}

// ---------------------------------------------------------------------------
// proj: Out = Attn @ Wout + bout.  LDS = W^T only (67.6 KB -> 2 WG/CU).
// A-frags straight from global; wave reads exactly the 32 rows it later writes
// (program-order read-before-write => alias-safe with Attn in d_out).
// ---------------------------------------------------------------------------
#define B_WSTR 528
#define LDS_P  67584

__global__ void __launch_bounds__(256, 2) proj_kernel(const unsigned short* Attn,
                                                      const float* __restrict__ Wout,
                                                      const float* __restrict__ bout,
                                                      float* Out){
  extern __shared__ char sm[];
  const int tid = threadIdx.x, w = tid>>6, lane = tid&63, half = lane>>5, l31 = lane&31;
  const int coff = half*16;
  const size_t r0 = (size_t)blockIdx.x * 128;
  if (tid < 128){                            // stage Wout^T [col][din] bf16
    const int col = tid;
    char* dst = sm + (size_t)col*B_WSTR;
    for (int d0 = 0; d0 < 256; d0 += 8){
      u32x4 v;
      v[0] = pkbf(Wout[(size_t)(d0+0)*DIMD + col], Wout[(size_t)(d0+1)*DIMD + col]);
      v[1] = pkbf(Wout[(size_t)(d0+2)*DIMD + col], Wout[(size_t)(d0+3)*DIMD + col]);
      v[2] = pkbf(Wout[(size_t)(d0+4)*DIMD + col], Wout[(size_t)(d0+5)*DIMD + col]);
      v[3] = pkbf(Wout[(size_t)(d0+6)*DIMD + col], Wout[(size_t)(d0+7)*DIMD + col]);
      *(u32x4*)(dst + d0*2) = v;
    }
  }
  __syncthreads();
  f32x16 acc[4];
#pragma unroll
  for (int nt = 0; nt < 4; ++nt){
    float bv = bout[nt*32 + l31];
#pragma unroll
    for (int k = 0; k < 16; ++k) acc[nt][k] = bv;
  }
  const char* Ab = (const char*)Attn + (r0 + w*32 + l31)*512;
#pragma unroll
  for (int ks = 0; ks < 16; ++ks){
    bf16x8 a = *(const bf16x8*)(Ab + ks*32 + coff);
#pragma unroll
    for (int nt = 0; nt < 4; ++nt){
      bf16x8 b = *(const bf16x8*)(sm + (size_t)(nt*32 + l31)*B_WSTR + ks*32 + coff);
      acc[nt] = MFMA32(a, b, acc[nt]);
    }
  }
#pragma unroll
  for (int nt = 0; nt < 4; ++nt){
    const int c = nt*32 + l31;
#pragma unroll
    for (int rq = 0; rq < 4; ++rq){
#pragma unroll
      for (int r = 0; r < 4; ++r){
        const int rr = w*32 + 8*rq + 4*half + r;
        Out[(r0 + rr)*DIMD + c] = acc[nt][4*rq + r];
      }
    }
  }
}

// ---------------------------------------------------------------------------
extern "C" void kernel_launch(void* const* d_in, const int* in_sizes, int n_in,
                              void* d_out, int out_size, void* d_ws, size_t ws_size,
                              hipStream_t stream){
  const float* X     = (const float*)d_in[0];
  const float* Wqkv  = (const float*)d_in[1];
  const float* Wout  = (const float*)d_in[2];
  const float* bout  = (const float*)d_in[3];
  const float* Wbias = (const float*)d_in[4];
  float* Out = (float*)d_out;

  // ws layout: Bws fp32 [0,1638400) | Xbf bf16 [1638400,27852800) | Wqkvt [.., 28049408)
  float*          Bws   = (float*)d_ws;
  unsigned short* Xbf   = (unsigned short*)((char*)d_ws + 1638400);
  unsigned*       XbfU  = (unsigned*)Xbf;
  unsigned short* Wqkvt = (unsigned short*)((char*)d_ws + 27852800);
  const bool use_bf = (ws_size >= (size_t)28049408);

  unsigned short* Attn = (unsigned short*)d_out;   // bf16 intermediate lives in d_out

  (void)hipFuncSetAttribute((const void*)proj_kernel,
                            hipFuncAttributeMaxDynamicSharedMemorySize, LDS_P);
  if (use_bf){
    (void)hipFuncSetAttribute((const void*)attn_kernel<true>,
                              hipFuncAttributeMaxDynamicSharedMemorySize, LDS_A);
    x2bf_bias<true><<<NPAIR/4, 256, 0, stream>>>(X, Wbias, Bws, XbfU);
    wpack<<<768*DIMD/256, 256, 0, stream>>>(Wqkv, Wqkvt);
    attn_kernel<true><<<dim3(NHEADS, NN), NTHR, LDS_A, stream>>>(X, Xbf, Wqkv, Wqkvt, Bws, Attn);
  } else {
    (void)hipFuncSetAttribute((const void*)attn_kernel<false>,
                              hipFuncAttributeMaxDynamicSharedMemorySize, LDS_A);
    x2bf_bias<false><<<NPAIR/4, 256, 0, stream>>>(X, Wbias, Bws, nullptr);
    attn_kernel<false><<<dim3(NHEADS, NN), NTHR, LDS_A, stream>>>(X, nullptr, Wqkv, nullptr, Bws, Attn);
  }
  proj_kernel<<<NPAIR/128, 256, LDS_P, stream>>>(Attn, Wout, bout, Out);
}

// Round 7
// 306.869 us; speedup vs baseline: 1.2972x; 1.1306x over previous
//
#include <hip/hip_runtime.h>

// TriangleAttention (starting node), MI355X gfx950.  Round 8.
// B=1, N=320, DIM=128, HEADS=4, DH=64, INNER=256. fp32 I/O, bf16 MFMA inside.
//
// Round-8 = r2 proven structure (512thr/8w, W staged, padded strides; 200us attn)
// + verified-safe opts + ONE isolated new change:
//  * exp2-domain softmax (verified r5/r7; bias pre-scaled log2e, exp->exp2).
//  * tree-ified softmax max/sum chains (r7).
//  * s_setprio(1) around MFMA clusters (r7; T5 regime: desynced attn waves).
//  * permlane32_swap BUILTIN replaces all __shfl_xor(..,32) (ds_bpermute).
//    NOTE: r3/r4 bisect proved the NaN was the v_cvt_pk asm (r4 NaN'd WITHOUT
//    permlane); permlane was never isolated. Lane mapping re-derived:
//    lswap(a,b) = {a.row0|b.row0, a.row1|b.row1} == old shfl+select paths.
//  * pkbf stays bit-math RTNE (cvt_pk asm banned).
//
// Pipeline:
//  x2bf_bias: wave per (q,k): X fp32 -> Xbf bf16 (ws) + bias GEMV*log2e -> Bws.
//  wpack:     Wqkv fp32 -> Wqkvt bf16 [col 768][din 128] (ws).
//  attn:      per (h,i), 512 thr / 8 waves. LDS K,Vt,W = 140 KB. 2 barriers.
//  proj:      Out = Attn @ Wout + bout. Attn bf16 lives IN d_out.

#define NN     320
#define DIMD   128
#define NHEADS 4
#define DH     64
#define INNERD 256
#define NPAIR  (NN*NN)
#define LOG2E  1.44269504f
#define SCL2   0.18033688f   // 0.125 * log2(e)

typedef __attribute__((ext_vector_type(8)))  short    bf16x8;
typedef __attribute__((ext_vector_type(16))) float    f32x16;
typedef __attribute__((ext_vector_type(4)))  unsigned u32x4;
typedef __attribute__((ext_vector_type(2)))  unsigned u32x2;

#define MFMA32(a,b,c) __builtin_amdgcn_mfma_f32_32x32x16_bf16((a),(b),(c),0,0,0)

#if defined(__has_builtin)
# if __has_builtin(__builtin_amdgcn_exp2f)
#  define HAVE_EXP2 1
# endif
# if __has_builtin(__builtin_amdgcn_permlane32_swap)
#  define HAVE_PLSWAP 1
# endif
#endif

// pack two f32 -> 2x bf16 (RTNE), proven bit-math version
__device__ __forceinline__ unsigned pkbf(float lo, float hi){
  unsigned a = __builtin_bit_cast(unsigned, lo);
  unsigned b = __builtin_bit_cast(unsigned, hi);
  a = (a + 0x7fffu + ((a>>16)&1u)) >> 16;
  b = (b + 0x7fffu + ((b>>16)&1u)) >> 16;
  return (a & 0xffffu) | (b<<16);
}
__device__ __forceinline__ unsigned short bf1(float f){
  unsigned u = __builtin_bit_cast(unsigned, f);
  return (unsigned short)((u + 0x7fffu + ((u>>16)&1u)) >> 16);
}
__device__ __forceinline__ float ex2(float x){
#ifdef HAVE_EXP2
  return __builtin_amdgcn_exp2f(x);
#else
  return exp2f(x);
#endif
}
// lane-half exchange: o[0] = {a.row0 | b.row0}, o[1] = {a.row1 | b.row1}
// (row0 = lanes 0-31, row1 = lanes 32-63)
__device__ __forceinline__ u32x2 lswap(unsigned a, unsigned b){
#ifdef HAVE_PLSWAP
  auto r = __builtin_amdgcn_permlane32_swap((int)a, (int)b, false, false);
  u32x2 o; o[0] = (unsigned)r[0]; o[1] = (unsigned)r[1]; return o;
#else
  unsigned sa = __shfl_xor(a, 32), sb = __shfl_xor(b, 32);
  const bool hiHalf = (threadIdx.x & 32) != 0;
  u32x2 o; o[0] = hiHalf ? sb : a; o[1] = hiHalf ? b : sa; return o;
#endif
}
__device__ __forceinline__ f32x16 z16(){
  f32x16 v;
#pragma unroll
  for (int k = 0; k < 16; ++k) v[k] = 0.0f;
  return v;
}

// ---------------------------------------------------------------------------
// x2bf_bias: wave per pair p=(q,k). Read 128 fp32 (float2/lane), write 64 dwords
// bf16 (XBF), and 4-head bias dot via fp32 shfl-reduce into Bws[h][q][k].
// Bias pre-scaled by log2(e) so attn softmax can use exp2 directly.
// ---------------------------------------------------------------------------
template<bool XBF>
__global__ void __launch_bounds__(256) x2bf_bias(const float* __restrict__ X,
                                                 const float* __restrict__ Wbias,
                                                 float* __restrict__ Bws,
                                                 unsigned* __restrict__ XbfU){
  const int tid  = threadIdx.x;
  const int lane = tid & 63;
  const int p    = blockIdx.x*4 + (tid >> 6);
  const int q    = p / NN, k = p - q*NN;
  float2 v = ((const float2*)(X + (size_t)p*DIMD))[lane];
  float4 w0 = ((const float4*)Wbias)[2*lane];
  float4 w1 = ((const float4*)Wbias)[2*lane+1];
  float4 s;
  s.x = v.x*w0.x + v.y*w1.x;
  s.y = v.x*w0.y + v.y*w1.y;
  s.z = v.x*w0.z + v.y*w1.z;
  s.w = v.x*w0.w + v.y*w1.w;
  if (XBF) XbfU[(size_t)p*64 + lane] = pkbf(v.x, v.y);
#pragma unroll
  for (int off = 32; off >= 1; off >>= 1){
    s.x += __shfl_xor(s.x, off);
    s.y += __shfl_xor(s.y, off);
    s.z += __shfl_xor(s.z, off);
    s.w += __shfl_xor(s.w, off);
  }
  if (lane == 0){
    Bws[(size_t)0*NPAIR + q*NN + k] = s.x*LOG2E;
    Bws[(size_t)1*NPAIR + q*NN + k] = s.y*LOG2E;
    Bws[(size_t)2*NPAIR + q*NN + k] = s.z*LOG2E;
    Bws[(size_t)3*NPAIR + q*NN + k] = s.w*LOG2E;
  }
}

// ---------------------------------------------------------------------------
// wpack: Wqkvt[c*128+d] = bf16(Wqkv[d*768+c]).  Coalesced reads, tiny scatter.
// ---------------------------------------------------------------------------
__global__ void __launch_bounds__(256) wpack(const float* __restrict__ Wqkv,
                                             unsigned short* __restrict__ Wqkvt){
  const int idx = blockIdx.x*256 + threadIdx.x;   // < 98304
  const int c = idx % 768, d = idx / 768;
  Wqkvt[c*DIMD + d] = bf1(Wqkv[idx]);
}

// ---------------------------------------------------------------------------
// attn kernel.  LDS map (bytes):
//   K   [320 j][64 d]  stride 144 :      0 ..  46080
//   Vt  [64 d][320 j]  stride 656 :  46080 ..  88064
//   W   [192 col][128 din] str 272:  88064 .. 140288   (q:0-63, k:64-127, v:128-191)
// ---------------------------------------------------------------------------
#define KOFF   0
#define VTOFF  46080
#define WOFF   88064
#define LDS_A  140288
#define KSTR   144
#define VTSTR  656
#define WSTR   272

template<bool XBF>
__device__ __forceinline__ bf16x8 xfrag(const float* Xf, const unsigned short* Xb,
                                        int row, int ks, int coff, int half){
  if constexpr (XBF){
    return *(const bf16x8*)((const char*)Xb + (size_t)row*256 + ks*32 + coff);
  } else {
    const float* p = Xf + (size_t)row*DIMD + ks*16 + half*8;
    float4 x0 = ((const float4*)p)[0], x1 = ((const float4*)p)[1];
    u32x4 v; v[0]=pkbf(x0.x,x0.y); v[1]=pkbf(x0.z,x0.w); v[2]=pkbf(x1.x,x1.y); v[3]=pkbf(x1.z,x1.w);
    return __builtin_bit_cast(bf16x8, v);
  }
}

template<bool XBF>
__global__ void __launch_bounds__(512, 2) attn_kernel(const float* __restrict__ X,
                                                      const unsigned short* __restrict__ Xbf,
                                                      const float* __restrict__ Wqkv,
                                                      const unsigned short* __restrict__ Wqkvt,
                                                      const float* __restrict__ Bws,
                                                      unsigned short* __restrict__ AttnOut){
  extern __shared__ char sm[];
  const int h = blockIdx.x, i = blockIdx.y;
  const int tid  = threadIdx.x;
  const int w    = tid >> 6;
  const int lane = tid & 63;
  const int half = lane >> 5;
  const int l31  = lane & 31;
  const int coff = half*16;

  // ---- stage W (q|k|v cols for this head), transposed [col][din] bf16
  if (XBF){
    for (int idx = tid; idx < 192*16; idx += 512){
      const int col = idx >> 4, seg = idx & 15;
      const int gcol = (col < 64)  ? (h*DH + col)
                     : (col < 128) ? (INNERD   + h*DH + (col-64))
                                   : (2*INNERD + h*DH + (col-128));
      u32x4 v = *(const u32x4*)(Wqkvt + (size_t)gcol*DIMD + seg*8);
      *(u32x4*)(sm + WOFF + (size_t)col*WSTR + seg*16) = v;
    }
  } else if (tid < 192){
    const int col  = tid;
    const int gcol = (col < 64)  ? (h*DH + col)
                   : (col < 128) ? (INNERD   + h*DH + (col-64))
                                 : (2*INNERD + h*DH + (col-128));
    char* dst = sm + WOFF + (size_t)col*WSTR;
    for (int d0 = 0; d0 < DIMD; d0 += 8){
      u32x4 v;
      v[0] = pkbf(Wqkv[(size_t)(d0+0)*768 + gcol], Wqkv[(size_t)(d0+1)*768 + gcol]);
      v[1] = pkbf(Wqkv[(size_t)(d0+2)*768 + gcol], Wqkv[(size_t)(d0+3)*768 + gcol]);
      v[2] = pkbf(Wqkv[(size_t)(d0+4)*768 + gcol], Wqkv[(size_t)(d0+5)*768 + gcol]);
      v[3] = pkbf(Wqkv[(size_t)(d0+6)*768 + gcol], Wqkv[(size_t)(d0+7)*768 + gcol]);
      *(u32x4*)(dst + d0*2) = v;
    }
  }
  __syncthreads();

  // ================= phase 1: 20 barrier-free wave-tasks (10 K, 10 V) ==========
  for (int r = 0; r < 3; ++r){
    const int t = w + 8*r;
    if (t >= 20) break;
    const bool isK = (t < 10);
    const int  jt  = isK ? t : t - 10;
    const int  jrow = jt*32 + l31;
    const int  grow = i*NN + jrow;
    f32x16 acc0 = z16(), acc1 = z16();
    if (isK){
      const char* A0 = sm + WOFF + (size_t)(64 + l31)*WSTR;
      const char* A1 = sm + WOFF + (size_t)(96 + l31)*WSTR;
#pragma unroll
      for (int ks = 0; ks < 8; ++ks){
        bf16x8 b  = xfrag<XBF>(X, Xbf, grow, ks, coff, half);
        bf16x8 a0 = *(const bf16x8*)(A0 + ks*32 + coff);
        bf16x8 a1 = *(const bf16x8*)(A1 + ks*32 + coff);
        acc0 = MFMA32(a0, b, acc0);
        acc1 = MFMA32(a1, b, acc1);
      }
#pragma unroll
      for (int rq = 0; rq < 4; ++rq){
        uint2 v0, v1;
        v0.x = pkbf(acc0[4*rq+0], acc0[4*rq+1]); v0.y = pkbf(acc0[4*rq+2], acc0[4*rq+3]);
        v1.x = pkbf(acc1[4*rq+0], acc1[4*rq+1]); v1.y = pkbf(acc1[4*rq+2], acc1[4*rq+3]);
        *(uint2*)(sm + KOFF + (size_t)jrow*KSTR +      (8*rq + 4*half)*2) = v0;
        *(uint2*)(sm + KOFF + (size_t)jrow*KSTR + 64 + (8*rq + 4*half)*2) = v1;
      }
    } else {
      const char* B0 = sm + WOFF + (size_t)(128 + l31)*WSTR;
      const char* B1 = sm + WOFF + (size_t)(160 + l31)*WSTR;
#pragma unroll
      for (int ks = 0; ks < 8; ++ks){
        bf16x8 a  = xfrag<XBF>(X, Xbf, grow, ks, coff, half);
        bf16x8 b0 = *(const bf16x8*)(B0 + ks*32 + coff);
        bf16x8 b1 = *(const bf16x8*)(B1 + ks*32 + coff);
        acc0 = MFMA32(a, b0, acc0);
        acc1 = MFMA32(a, b1, acc1);
      }
#pragma unroll
      for (int rq = 0; rq < 4; ++rq){
        uint2 v0, v1;
        v0.x = pkbf(acc0[4*rq+0], acc0[4*rq+1]); v0.y = pkbf(acc0[4*rq+2], acc0[4*rq+3]);
        v1.x = pkbf(acc1[4*rq+0], acc1[4*rq+1]); v1.y = pkbf(acc1[4*rq+2], acc1[4*rq+3]);
        *(uint2*)(sm + VTOFF + (size_t)(     l31)*VTSTR + (jt*32 + 8*rq + 4*half)*2) = v0;
        *(uint2*)(sm + VTOFF + (size_t)(32 + l31)*VTSTR + (jt*32 + 8*rq + 4*half)*2) = v1;
      }
    }
  }
  __syncthreads();

  // ================= phase 2: 10 q-tile wave-tasks over 8 waves ===============
  for (int rep = 0; rep < 2; ++rep){
    const int qt = w + 8*rep;
    if (qt >= 10) break;
    const int q = qt*32 + l31;
    // ---- Q-proj: D col = q, rows = d
    f32x16 qa0 = z16(), qa1 = z16();
#pragma unroll
    for (int ks = 0; ks < 8; ++ks){
      bf16x8 b  = xfrag<XBF>(X, Xbf, i*NN + q, ks, coff, half);
      bf16x8 a0 = *(const bf16x8*)(sm + WOFF + (size_t)(     l31)*WSTR + ks*32 + coff);
      bf16x8 a1 = *(const bf16x8*)(sm + WOFF + (size_t)(32 + l31)*WSTR + ks*32 + coff);
      qa0 = MFMA32(a0, b, qa0);
      qa1 = MFMA32(a1, b, qa1);
    }
    // ---- build qf[4] (B-frags over d) in-register from D-layout via lswap
    bf16x8 qf[4];
    {
      unsigned a0 = pkbf(qa0[0],qa0[1]),  a0b = pkbf(qa0[2],qa0[3]);
      unsigned a1 = pkbf(qa0[4],qa0[5]),  a1b = pkbf(qa0[6],qa0[7]);
      unsigned a2 = pkbf(qa0[8],qa0[9]),  a2b = pkbf(qa0[10],qa0[11]);
      unsigned a3 = pkbf(qa0[12],qa0[13]),a3b = pkbf(qa0[14],qa0[15]);
      unsigned b0 = pkbf(qa1[0],qa1[1]),  b0b = pkbf(qa1[2],qa1[3]);
      unsigned b1 = pkbf(qa1[4],qa1[5]),  b1b = pkbf(qa1[6],qa1[7]);
      unsigned b2 = pkbf(qa1[8],qa1[9]),  b2b = pkbf(qa1[10],qa1[11]);
      unsigned b3 = pkbf(qa1[12],qa1[13]),b3b = pkbf(qa1[14],qa1[15]);
      u32x2 s0 = lswap(a0,a1), s0b = lswap(a0b,a1b);
      u32x2 s1 = lswap(a2,a3), s1b = lswap(a2b,a3b);
      u32x2 s2 = lswap(b0,b1), s2b = lswap(b0b,b1b);
      u32x2 s3 = lswap(b2,b3), s3b = lswap(b2b,b3b);
      u32x4 f;
      f[0]=s0[0]; f[1]=s0b[0]; f[2]=s0[1]; f[3]=s0b[1]; qf[0]=__builtin_bit_cast(bf16x8,f);
      f[0]=s1[0]; f[1]=s1b[0]; f[2]=s1[1]; f[3]=s1b[1]; qf[1]=__builtin_bit_cast(bf16x8,f);
      f[0]=s2[0]; f[1]=s2b[0]; f[2]=s2[1]; f[3]=s2b[1]; qf[2]=__builtin_bit_cast(bf16x8,f);
      f[0]=s3[0]; f[1]=s3b[0]; f[2]=s3[1]; f[3]=s3b[1]; qf[3]=__builtin_bit_cast(bf16x8,f);
    }
    // ---- scores^T: S[j][q], D col = q = l31, rows = j
    f32x16 S[10];
#pragma unroll
    for (int jt = 0; jt < 10; ++jt) S[jt] = z16();
    __builtin_amdgcn_s_setprio(1);
#pragma unroll
    for (int jt = 0; jt < 10; ++jt){
#pragma unroll
      for (int c = 0; c < 4; ++c){
        bf16x8 a = *(const bf16x8*)(sm + KOFF + (size_t)(jt*32 + l31)*KSTR + c*32 + coff);
        S[jt] = MFMA32(a, qf[c], S[jt]);
      }
    }
    __builtin_amdgcn_s_setprio(0);
    // ---- scale + bias in exp2 domain + softmax over j (tree-reduced chains)
    const float4* Bf = (const float4*)(Bws + (size_t)h*NPAIR + (size_t)q*NN);
    float m = -3.0e38f;
#pragma unroll
    for (int jt = 0; jt < 10; ++jt){
      float mj = -3.0e38f;
#pragma unroll
      for (int rq = 0; rq < 4; ++rq){
        float4 bv = Bf[jt*8 + 2*rq + half];
        float v0 = S[jt][4*rq+0]*SCL2 + bv.x;
        float v1 = S[jt][4*rq+1]*SCL2 + bv.y;
        float v2 = S[jt][4*rq+2]*SCL2 + bv.z;
        float v3 = S[jt][4*rq+3]*SCL2 + bv.w;
        S[jt][4*rq+0]=v0; S[jt][4*rq+1]=v1; S[jt][4*rq+2]=v2; S[jt][4*rq+3]=v3;
        mj = fmaxf(mj, fmaxf(fmaxf(v0,v1), fmaxf(v2,v3)));
      }
      m = fmaxf(m, mj);
    }
    {
      unsigned mu = __builtin_bit_cast(unsigned, m);
      u32x2 mm = lswap(mu, mu);
      m = fmaxf(__builtin_bit_cast(float, mm[0]), __builtin_bit_cast(float, mm[1]));
    }
    float l = 0.0f;
#pragma unroll
    for (int jt = 0; jt < 10; ++jt){
      float t0 = 0.f, t1 = 0.f, t2 = 0.f, t3 = 0.f;
#pragma unroll
      for (int k = 0; k < 4; ++k){
        float e0 = ex2(S[jt][4*k+0] - m);
        float e1 = ex2(S[jt][4*k+1] - m);
        float e2 = ex2(S[jt][4*k+2] - m);
        float e3 = ex2(S[jt][4*k+3] - m);
        S[jt][4*k+0]=e0; S[jt][4*k+1]=e1; S[jt][4*k+2]=e2; S[jt][4*k+3]=e3;
        t0 += e0; t1 += e1; t2 += e2; t3 += e3;
      }
      l += (t0 + t1) + (t2 + t3);
    }
    {
      unsigned lu = __builtin_bit_cast(unsigned, l);
      u32x2 ll = lswap(lu, lu);
      l = __builtin_bit_cast(float, ll[0]) + __builtin_bit_cast(float, ll[1]);
    }
    const float rl = 1.0f / l;
    // ---- PV: O^T[d][q] += Vt[d][j] * P^T[j][q]; P-frags via lswap.
    f32x16 o0 = z16(), o1 = z16();
#pragma unroll
    for (int jt = 0; jt < 10; ++jt){
      unsigned P0a = pkbf(S[jt][0], S[jt][1]),  P0b = pkbf(S[jt][2], S[jt][3]);
      unsigned P1a = pkbf(S[jt][4], S[jt][5]),  P1b = pkbf(S[jt][6], S[jt][7]);
      unsigned P2a = pkbf(S[jt][8], S[jt][9]),  P2b = pkbf(S[jt][10],S[jt][11]);
      unsigned P3a = pkbf(S[jt][12],S[jt][13]), P3b = pkbf(S[jt][14],S[jt][15]);
      u32x2 e0 = lswap(P0a,P1a), e1 = lswap(P0b,P1b);
      u32x2 d0 = lswap(P2a,P3a), d1 = lswap(P2b,P3b);
      u32x4 fe, fo;
      fe[0]=e0[0]; fe[1]=e1[0]; fe[2]=e0[1]; fe[3]=e1[1];
      fo[0]=d0[0]; fo[1]=d1[0]; fo[2]=d0[1]; fo[3]=d1[1];
      bf16x8 pe = __builtin_bit_cast(bf16x8, fe);
      bf16x8 po = __builtin_bit_cast(bf16x8, fo);
      bf16x8 va0e = *(const bf16x8*)(sm + VTOFF + (size_t)(     l31)*VTSTR + jt*64 + coff);
      bf16x8 va1e = *(const bf16x8*)(sm + VTOFF + (size_t)(32 + l31)*VTSTR + jt*64 + coff);
      bf16x8 va0o = *(const bf16x8*)(sm + VTOFF + (size_t)(     l31)*VTSTR + jt*64 + 32 + coff);
      bf16x8 va1o = *(const bf16x8*)(sm + VTOFF + (size_t)(32 + l31)*VTSTR + jt*64 + 32 + coff);
      __builtin_amdgcn_s_setprio(1);
      o0 = MFMA32(va0e, pe, o0);
      o1 = MFMA32(va1e, pe, o1);
      o0 = MFMA32(va0o, po, o0);
      o1 = MFMA32(va1o, po, o1);
      __builtin_amdgcn_s_setprio(0);
    }
    // ---- epilogue
    const size_t rowbase = (((size_t)i*NN) + q)*INNERD + h*DH;
#pragma unroll
    for (int rq = 0; rq < 4; ++rq){
      const int dd = 8*rq + 4*half;
      uint2 v0, v1;
      v0.x = pkbf(o0[4*rq+0]*rl, o0[4*rq+1]*rl); v0.y = pkbf(o0[4*rq+2]*rl, o0[4*rq+3]*rl);
      v1.x = pkbf(o1[4*rq+0]*rl, o1[4*rq+1]*rl); v1.y = pkbf(o1[4*rq+2]*rl, o1[4*rq+3]*rl);
      *(uint2*)(AttnOut + rowbase + dd)      = v0;
      *(uint2*)(AttnOut + rowbase + 32 + dd) = v1;
    }
  }
}

// ---------------------------------------------------------------------------
// proj: Out = Attn @ Wout + bout.  LDS = W^T only (67.6 KB -> 2 WG/CU).
// A-frags straight from global; wave reads exactly the 32 rows it later writes
// (program-order read-before-write => alias-safe with Attn in d_out).
// ---------------------------------------------------------------------------
#define B_WSTR 528
#define LDS_P  67584

__global__ void __launch_bounds__(256, 2) proj_kernel(const unsigned short* Attn,
                                                      const float* __restrict__ Wout,
                                                      const float* __restrict__ bout,
                                                      float* Out){
  extern __shared__ char sm[];
  const int tid = threadIdx.x, w = tid>>6, lane = tid&63, half = lane>>5, l31 = lane&31;
  const int coff = half*16;
  const size_t r0 = (size_t)blockIdx.x * 128;
  if (tid < 128){                            // stage Wout^T [col][din] bf16
    const int col = tid;
    char* dst = sm + (size_t)col*B_WSTR;
    for (int d0 = 0; d0 < 256; d0 += 8){
      u32x4 v;
      v[0] = pkbf(Wout[(size_t)(d0+0)*DIMD + col], Wout[(size_t)(d0+1)*DIMD + col]);
      v[1] = pkbf(Wout[(size_t)(d0+2)*DIMD + col], Wout[(size_t)(d0+3)*DIMD + col]);
      v[2] = pkbf(Wout[(size_t)(d0+4)*DIMD + col], Wout[(size_t)(d0+5)*DIMD + col]);
      v[3] = pkbf(Wout[(size_t)(d0+6)*DIMD + col], Wout[(size_t)(d0+7)*DIMD + col]);
      *(u32x4*)(dst + d0*2) = v;
    }
  }
  __syncthreads();
  f32x16 acc[4];
#pragma unroll
  for (int nt = 0; nt < 4; ++nt){
    float bv = bout[nt*32 + l31];
#pragma unroll
    for (int k = 0; k < 16; ++k) acc[nt][k] = bv;
  }
  const char* Ab = (const char*)Attn + (r0 + w*32 + l31)*512;
#pragma unroll
  for (int ks = 0; ks < 16; ++ks){
    bf16x8 a = *(const bf16x8*)(Ab + ks*32 + coff);
#pragma unroll
    for (int nt = 0; nt < 4; ++nt){
      bf16x8 b = *(const bf16x8*)(sm + (size_t)(nt*32 + l31)*B_WSTR + ks*32 + coff);
      acc[nt] = MFMA32(a, b, acc[nt]);
    }
  }
#pragma unroll
  for (int nt = 0; nt < 4; ++nt){
    const int c = nt*32 + l31;
#pragma unroll
    for (int rq = 0; rq < 4; ++rq){
#pragma unroll
      for (int r = 0; r < 4; ++r){
        const int rr = w*32 + 8*rq + 4*half + r;
        Out[(r0 + rr)*DIMD + c] = acc[nt][4*rq + r];
      }
    }
  }
}

// ---------------------------------------------------------------------------
extern "C" void kernel_launch(void* const* d_in, const int* in_sizes, int n_in,
                              void* d_out, int out_size, void* d_ws, size_t ws_size,
                              hipStream_t stream){
  const float* X     = (const float*)d_in[0];
  const float* Wqkv  = (const float*)d_in[1];
  const float* Wout  = (const float*)d_in[2];
  const float* bout  = (const float*)d_in[3];
  const float* Wbias = (const float*)d_in[4];
  float* Out = (float*)d_out;

  // ws layout: Bws fp32 [0,1638400) | Xbf bf16 [1638400,27852800) | Wqkvt [.., 28049408)
  float*          Bws   = (float*)d_ws;
  unsigned short* Xbf   = (unsigned short*)((char*)d_ws + 1638400);
  unsigned*       XbfU  = (unsigned*)Xbf;
  unsigned short* Wqkvt = (unsigned short*)((char*)d_ws + 27852800);
  const bool use_bf = (ws_size >= (size_t)28049408);

  unsigned short* Attn = (unsigned short*)d_out;   // bf16 intermediate lives in d_out

  (void)hipFuncSetAttribute((const void*)proj_kernel,
                            hipFuncAttributeMaxDynamicSharedMemorySize, LDS_P);
  if (use_bf){
    (void)hipFuncSetAttribute((const void*)attn_kernel<true>,
                              hipFuncAttributeMaxDynamicSharedMemorySize, LDS_A);
    x2bf_bias<true><<<NPAIR/4, 256, 0, stream>>>(X, Wbias, Bws, XbfU);
    wpack<<<768*DIMD/256, 256, 0, stream>>>(Wqkv, Wqkvt);
    attn_kernel<true><<<dim3(NHEADS, NN), 512, LDS_A, stream>>>(X, Xbf, Wqkv, Wqkvt, Bws, Attn);
  } else {
    (void)hipFuncSetAttribute((const void*)attn_kernel<false>,
                              hipFuncAttributeMaxDynamicSharedMemorySize, LDS_A);
    x2bf_bias<false><<<NPAIR/4, 256, 0, stream>>>(X, Wbias, Bws, nullptr);
    attn_kernel<false><<<dim3(NHEADS, NN), 512, LDS_A, stream>>>(X, nullptr, Wqkv, nullptr, Bws, Attn);
  }
  proj_kernel<<<NPAIR/128, 256, LDS_P, stream>>>(Attn, Wout, bout, Out);
}

// Round 8
// 298.144 us; speedup vs baseline: 1.3352x; 1.0293x over previous
//
#include <hip/hip_runtime.h>

// TriangleAttention (starting node), MI355X gfx950.  Round 9.
// B=1, N=320, DIM=128, HEADS=4, DH=64, INNER=256. fp32 I/O, bf16 MFMA inside.
//
// Round-9 = r8 attn (170us, untouched) + side-kernel overhaul:
//  * x2bf_bias: 16 lanes/pair (4 pairs/wave, 6400 blocks). float4x2 loads,
//    4-step shfl tree (was 6-step x4 = 24 dep shfls/pair -> 4/pair), 16B Xbf store.
//  * wpack also emits Woutt bf16 [col 128][din 256] (one-time Wout transpose);
//    proj<WT=true> stages it with coalesced u32x4 copies on all 256 threads
//    (was: every block re-transposing via 32768 strided scalar loads on 128 thr).
//    Guarded by ws_size >= 28114944; falls back to old path otherwise.
//  * attn kernel byte-identical to r8 (permlane32_swap + exp2 + setprio; 170us).

#define NN     320
#define DIMD   128
#define NHEADS 4
#define DH     64
#define INNERD 256
#define NPAIR  (NN*NN)
#define LOG2E  1.44269504f
#define SCL2   0.18033688f   // 0.125 * log2(e)

typedef __attribute__((ext_vector_type(8)))  short    bf16x8;
typedef __attribute__((ext_vector_type(16))) float    f32x16;
typedef __attribute__((ext_vector_type(4)))  unsigned u32x4;
typedef __attribute__((ext_vector_type(2)))  unsigned u32x2;

#define MFMA32(a,b,c) __builtin_amdgcn_mfma_f32_32x32x16_bf16((a),(b),(c),0,0,0)

#if defined(__has_builtin)
# if __has_builtin(__builtin_amdgcn_exp2f)
#  define HAVE_EXP2 1
# endif
# if __has_builtin(__builtin_amdgcn_permlane32_swap)
#  define HAVE_PLSWAP 1
# endif
#endif

// pack two f32 -> 2x bf16 (RTNE), proven bit-math version
__device__ __forceinline__ unsigned pkbf(float lo, float hi){
  unsigned a = __builtin_bit_cast(unsigned, lo);
  unsigned b = __builtin_bit_cast(unsigned, hi);
  a = (a + 0x7fffu + ((a>>16)&1u)) >> 16;
  b = (b + 0x7fffu + ((b>>16)&1u)) >> 16;
  return (a & 0xffffu) | (b<<16);
}
__device__ __forceinline__ unsigned short bf1(float f){
  unsigned u = __builtin_bit_cast(unsigned, f);
  return (unsigned short)((u + 0x7fffu + ((u>>16)&1u)) >> 16);
}
__device__ __forceinline__ float ex2(float x){
#ifdef HAVE_EXP2
  return __builtin_amdgcn_exp2f(x);
#else
  return exp2f(x);
#endif
}
// lane-half exchange: o[0] = {a.row0 | b.row0}, o[1] = {a.row1 | b.row1}
__device__ __forceinline__ u32x2 lswap(unsigned a, unsigned b){
#ifdef HAVE_PLSWAP
  auto r = __builtin_amdgcn_permlane32_swap((int)a, (int)b, false, false);
  u32x2 o; o[0] = (unsigned)r[0]; o[1] = (unsigned)r[1]; return o;
#else
  unsigned sa = __shfl_xor(a, 32), sb = __shfl_xor(b, 32);
  const bool hiHalf = (threadIdx.x & 32) != 0;
  u32x2 o; o[0] = hiHalf ? sb : a; o[1] = hiHalf ? b : sa; return o;
#endif
}
__device__ __forceinline__ f32x16 z16(){
  f32x16 v;
#pragma unroll
  for (int k = 0; k < 16; ++k) v[k] = 0.0f;
  return v;
}

// ---------------------------------------------------------------------------
// x2bf_bias: 16 lanes per pair, 4 pairs/wave, 16 pairs/block (6400 blocks).
// Lane t16 of group g loads X[p][t16*8 .. +7] (2x float4, 512B/group coalesced),
// writes 4 packed dwords (16B) of Xbf, and accumulates the 4-head bias dot,
// reduced over 16 lanes via a 4-step shfl_xor tree. Bias pre-scaled by log2e.
// ---------------------------------------------------------------------------
template<bool XBF>
__global__ void __launch_bounds__(256) x2bf_bias(const float* __restrict__ X,
                                                 const float* __restrict__ Wbias,
                                                 float* __restrict__ Bws,
                                                 unsigned* __restrict__ XbfU){
  const int tid = threadIdx.x;
  const int g   = tid >> 4;            // 0..15 : pair within block
  const int t16 = tid & 15;
  const int p   = blockIdx.x*16 + g;
  const float4* Xp = (const float4*)(X + (size_t)p*DIMD + t16*8);
  float4 x0 = Xp[0], x1 = Xp[1];
  const float4* Wb = (const float4*)Wbias;    // [128][4] fp32 rows
  float4 s = {0.f, 0.f, 0.f, 0.f};
  float xv[8] = {x0.x, x0.y, x0.z, x0.w, x1.x, x1.y, x1.z, x1.w};
#pragma unroll
  for (int j = 0; j < 8; ++j){
    float4 wj = Wb[t16*8 + j];
    s.x += xv[j]*wj.x;
    s.y += xv[j]*wj.y;
    s.z += xv[j]*wj.z;
    s.w += xv[j]*wj.w;
  }
  if (XBF){
    u32x4 v;
    v[0] = pkbf(x0.x, x0.y); v[1] = pkbf(x0.z, x0.w);
    v[2] = pkbf(x1.x, x1.y); v[3] = pkbf(x1.z, x1.w);
    *(u32x4*)(XbfU + (size_t)p*64 + t16*4) = v;
  }
#pragma unroll
  for (int off = 8; off >= 1; off >>= 1){
    s.x += __shfl_xor(s.x, off);
    s.y += __shfl_xor(s.y, off);
    s.z += __shfl_xor(s.z, off);
    s.w += __shfl_xor(s.w, off);
  }
  if (t16 == 0){
    Bws[(size_t)0*NPAIR + p] = s.x*LOG2E;
    Bws[(size_t)1*NPAIR + p] = s.y*LOG2E;
    Bws[(size_t)2*NPAIR + p] = s.z*LOG2E;
    Bws[(size_t)3*NPAIR + p] = s.w*LOG2E;
  }
}

// ---------------------------------------------------------------------------
// wpack: Wqkvt[c*128+d] = bf16(Wqkv[d*768+c])            (idx < 98304)
//        Woutt[c*256+d] = bf16(Wout[d*128+c])            (idx >= 98304, if grid=512)
// Coalesced reads, tiny scatter writes.
// ---------------------------------------------------------------------------
__global__ void __launch_bounds__(256) wpack(const float* __restrict__ Wqkv,
                                             unsigned short* __restrict__ Wqkvt,
                                             const float* __restrict__ Wout,
                                             unsigned short* __restrict__ Woutt){
  const int idx = blockIdx.x*256 + threadIdx.x;
  if (idx < 98304){
    const int c = idx % 768, d = idx / 768;
    Wqkvt[c*DIMD + d] = bf1(Wqkv[idx]);
  } else {
    const int i2 = idx - 98304;          // = d*128 + c, < 32768
    const int c = i2 & 127, d = i2 >> 7;
    Woutt[c*INNERD + d] = bf1(Wout[i2]);
  }
}

// ---------------------------------------------------------------------------
// attn kernel (UNCHANGED from r8).  LDS map (bytes):
//   K   [320 j][64 d]  stride 144 :      0 ..  46080
//   Vt  [64 d][320 j]  stride 656 :  46080 ..  88064
//   W   [192 col][128 din] str 272:  88064 .. 140288   (q:0-63, k:64-127, v:128-191)
// ---------------------------------------------------------------------------
#define KOFF   0
#define VTOFF  46080
#define WOFF   88064
#define LDS_A  140288
#define KSTR   144
#define VTSTR  656
#define WSTR   272

template<bool XBF>
__device__ __forceinline__ bf16x8 xfrag(const float* Xf, const unsigned short* Xb,
                                        int row, int ks, int coff, int half){
  if constexpr (XBF){
    return *(const bf16x8*)((const char*)Xb + (size_t)row*256 + ks*32 + coff);
  } else {
    const float* p = Xf + (size_t)row*DIMD + ks*16 + half*8;
    float4 x0 = ((const float4*)p)[0], x1 = ((const float4*)p)[1];
    u32x4 v; v[0]=pkbf(x0.x,x0.y); v[1]=pkbf(x0.z,x0.w); v[2]=pkbf(x1.x,x1.y); v[3]=pkbf(x1.z,x1.w);
    return __builtin_bit_cast(bf16x8, v);
  }
}

template<bool XBF>
__global__ void __launch_bounds__(512, 2) attn_kernel(const float* __restrict__ X,
                                                      const unsigned short* __restrict__ Xbf,
                                                      const float* __restrict__ Wqkv,
                                                      const unsigned short* __restrict__ Wqkvt,
                                                      const float* __restrict__ Bws,
                                                      unsigned short* __restrict__ AttnOut){
  extern __shared__ char sm[];
  const int h = blockIdx.x, i = blockIdx.y;
  const int tid  = threadIdx.x;
  const int w    = tid >> 6;
  const int lane = tid & 63;
  const int half = lane >> 5;
  const int l31  = lane & 31;
  const int coff = half*16;

  // ---- stage W (q|k|v cols for this head), transposed [col][din] bf16
  if (XBF){
    for (int idx = tid; idx < 192*16; idx += 512){
      const int col = idx >> 4, seg = idx & 15;
      const int gcol = (col < 64)  ? (h*DH + col)
                     : (col < 128) ? (INNERD   + h*DH + (col-64))
                                   : (2*INNERD + h*DH + (col-128));
      u32x4 v = *(const u32x4*)(Wqkvt + (size_t)gcol*DIMD + seg*8);
      *(u32x4*)(sm + WOFF + (size_t)col*WSTR + seg*16) = v;
    }
  } else if (tid < 192){
    const int col  = tid;
    const int gcol = (col < 64)  ? (h*DH + col)
                   : (col < 128) ? (INNERD   + h*DH + (col-64))
                                 : (2*INNERD + h*DH + (col-128));
    char* dst = sm + WOFF + (size_t)col*WSTR;
    for (int d0 = 0; d0 < DIMD; d0 += 8){
      u32x4 v;
      v[0] = pkbf(Wqkv[(size_t)(d0+0)*768 + gcol], Wqkv[(size_t)(d0+1)*768 + gcol]);
      v[1] = pkbf(Wqkv[(size_t)(d0+2)*768 + gcol], Wqkv[(size_t)(d0+3)*768 + gcol]);
      v[2] = pkbf(Wqkv[(size_t)(d0+4)*768 + gcol], Wqkv[(size_t)(d0+5)*768 + gcol]);
      v[3] = pkbf(Wqkv[(size_t)(d0+6)*768 + gcol], Wqkv[(size_t)(d0+7)*768 + gcol]);
      *(u32x4*)(dst + d0*2) = v;
    }
  }
  __syncthreads();

  // ================= phase 1: 20 barrier-free wave-tasks (10 K, 10 V) ==========
  for (int r = 0; r < 3; ++r){
    const int t = w + 8*r;
    if (t >= 20) break;
    const bool isK = (t < 10);
    const int  jt  = isK ? t : t - 10;
    const int  jrow = jt*32 + l31;
    const int  grow = i*NN + jrow;
    f32x16 acc0 = z16(), acc1 = z16();
    if (isK){
      const char* A0 = sm + WOFF + (size_t)(64 + l31)*WSTR;
      const char* A1 = sm + WOFF + (size_t)(96 + l31)*WSTR;
#pragma unroll
      for (int ks = 0; ks < 8; ++ks){
        bf16x8 b  = xfrag<XBF>(X, Xbf, grow, ks, coff, half);
        bf16x8 a0 = *(const bf16x8*)(A0 + ks*32 + coff);
        bf16x8 a1 = *(const bf16x8*)(A1 + ks*32 + coff);
        acc0 = MFMA32(a0, b, acc0);
        acc1 = MFMA32(a1, b, acc1);
      }
#pragma unroll
      for (int rq = 0; rq < 4; ++rq){
        uint2 v0, v1;
        v0.x = pkbf(acc0[4*rq+0], acc0[4*rq+1]); v0.y = pkbf(acc0[4*rq+2], acc0[4*rq+3]);
        v1.x = pkbf(acc1[4*rq+0], acc1[4*rq+1]); v1.y = pkbf(acc1[4*rq+2], acc1[4*rq+3]);
        *(uint2*)(sm + KOFF + (size_t)jrow*KSTR +      (8*rq + 4*half)*2) = v0;
        *(uint2*)(sm + KOFF + (size_t)jrow*KSTR + 64 + (8*rq + 4*half)*2) = v1;
      }
    } else {
      const char* B0 = sm + WOFF + (size_t)(128 + l31)*WSTR;
      const char* B1 = sm + WOFF + (size_t)(160 + l31)*WSTR;
#pragma unroll
      for (int ks = 0; ks < 8; ++ks){
        bf16x8 a  = xfrag<XBF>(X, Xbf, grow, ks, coff, half);
        bf16x8 b0 = *(const bf16x8*)(B0 + ks*32 + coff);
        bf16x8 b1 = *(const bf16x8*)(B1 + ks*32 + coff);
        acc0 = MFMA32(a, b0, acc0);
        acc1 = MFMA32(a, b1, acc1);
      }
#pragma unroll
      for (int rq = 0; rq < 4; ++rq){
        uint2 v0, v1;
        v0.x = pkbf(acc0[4*rq+0], acc0[4*rq+1]); v0.y = pkbf(acc0[4*rq+2], acc0[4*rq+3]);
        v1.x = pkbf(acc1[4*rq+0], acc1[4*rq+1]); v1.y = pkbf(acc1[4*rq+2], acc1[4*rq+3]);
        *(uint2*)(sm + VTOFF + (size_t)(     l31)*VTSTR + (jt*32 + 8*rq + 4*half)*2) = v0;
        *(uint2*)(sm + VTOFF + (size_t)(32 + l31)*VTSTR + (jt*32 + 8*rq + 4*half)*2) = v1;
      }
    }
  }
  __syncthreads();

  // ================= phase 2: 10 q-tile wave-tasks over 8 waves ===============
  for (int rep = 0; rep < 2; ++rep){
    const int qt = w + 8*rep;
    if (qt >= 10) break;
    const int q = qt*32 + l31;
    // ---- Q-proj: D col = q, rows = d
    f32x16 qa0 = z16(), qa1 = z16();
#pragma unroll
    for (int ks = 0; ks < 8; ++ks){
      bf16x8 b  = xfrag<XBF>(X, Xbf, i*NN + q, ks, coff, half);
      bf16x8 a0 = *(const bf16x8*)(sm + WOFF + (size_t)(     l31)*WSTR + ks*32 + coff);
      bf16x8 a1 = *(const bf16x8*)(sm + WOFF + (size_t)(32 + l31)*WSTR + ks*32 + coff);
      qa0 = MFMA32(a0, b, qa0);
      qa1 = MFMA32(a1, b, qa1);
    }
    // ---- build qf[4] (B-frags over d) in-register from D-layout via lswap
    bf16x8 qf[4];
    {
      unsigned a0 = pkbf(qa0[0],qa0[1]),  a0b = pkbf(qa0[2],qa0[3]);
      unsigned a1 = pkbf(qa0[4],qa0[5]),  a1b = pkbf(qa0[6],qa0[7]);
      unsigned a2 = pkbf(qa0[8],qa0[9]),  a2b = pkbf(qa0[10],qa0[11]);
      unsigned a3 = pkbf(qa0[12],qa0[13]),a3b = pkbf(qa0[14],qa0[15]);
      unsigned b0 = pkbf(qa1[0],qa1[1]),  b0b = pkbf(qa1[2],qa1[3]);
      unsigned b1 = pkbf(qa1[4],qa1[5]),  b1b = pkbf(qa1[6],qa1[7]);
      unsigned b2 = pkbf(qa1[8],qa1[9]),  b2b = pkbf(qa1[10],qa1[11]);
      unsigned b3 = pkbf(qa1[12],qa1[13]),b3b = pkbf(qa1[14],qa1[15]);
      u32x2 s0 = lswap(a0,a1), s0b = lswap(a0b,a1b);
      u32x2 s1 = lswap(a2,a3), s1b = lswap(a2b,a3b);
      u32x2 s2 = lswap(b0,b1), s2b = lswap(b0b,b1b);
      u32x2 s3 = lswap(b2,b3), s3b = lswap(b2b,b3b);
      u32x4 f;
      f[0]=s0[0]; f[1]=s0b[0]; f[2]=s0[1]; f[3]=s0b[1]; qf[0]=__builtin_bit_cast(bf16x8,f);
      f[0]=s1[0]; f[1]=s1b[0]; f[2]=s1[1]; f[3]=s1b[1]; qf[1]=__builtin_bit_cast(bf16x8,f);
      f[0]=s2[0]; f[1]=s2b[0]; f[2]=s2[1]; f[3]=s2b[1]; qf[2]=__builtin_bit_cast(bf16x8,f);
      f[0]=s3[0]; f[1]=s3b[0]; f[2]=s3[1]; f[3]=s3b[1]; qf[3]=__builtin_bit_cast(bf16x8,f);
    }
    // ---- scores^T: S[j][q], D col = q = l31, rows = j
    f32x16 S[10];
#pragma unroll
    for (int jt = 0; jt < 10; ++jt) S[jt] = z16();
    __builtin_amdgcn_s_setprio(1);
#pragma unroll
    for (int jt = 0; jt < 10; ++jt){
#pragma unroll
      for (int c = 0; c < 4; ++c){
        bf16x8 a = *(const bf16x8*)(sm + KOFF + (size_t)(jt*32 + l31)*KSTR + c*32 + coff);
        S[jt] = MFMA32(a, qf[c], S[jt]);
      }
    }
    __builtin_amdgcn_s_setprio(0);
    // ---- scale + bias in exp2 domain + softmax over j (tree-reduced chains)
    const float4* Bf = (const float4*)(Bws + (size_t)h*NPAIR + (size_t)q*NN);
    float m = -3.0e38f;
#pragma unroll
    for (int jt = 0; jt < 10; ++jt){
      float mj = -3.0e38f;
#pragma unroll
      for (int rq = 0; rq < 4; ++rq){
        float4 bv = Bf[jt*8 + 2*rq + half];
        float v0 = S[jt][4*rq+0]*SCL2 + bv.x;
        float v1 = S[jt][4*rq+1]*SCL2 + bv.y;
        float v2 = S[jt][4*rq+2]*SCL2 + bv.z;
        float v3 = S[jt][4*rq+3]*SCL2 + bv.w;
        S[jt][4*rq+0]=v0; S[jt][4*rq+1]=v1; S[jt][4*rq+2]=v2; S[jt][4*rq+3]=v3;
        mj = fmaxf(mj, fmaxf(fmaxf(v0,v1), fmaxf(v2,v3)));
      }
      m = fmaxf(m, mj);
    }
    {
      unsigned mu = __builtin_bit_cast(unsigned, m);
      u32x2 mm = lswap(mu, mu);
      m = fmaxf(__builtin_bit_cast(float, mm[0]), __builtin_bit_cast(float, mm[1]));
    }
    float l = 0.0f;
#pragma unroll
    for (int jt = 0; jt < 10; ++jt){
      float t0 = 0.f, t1 = 0.f, t2 = 0.f, t3 = 0.f;
#pragma unroll
      for (int k = 0; k < 4; ++k){
        float e0 = ex2(S[jt][4*k+0] - m);
        float e1 = ex2(S[jt][4*k+1] - m);
        float e2 = ex2(S[jt][4*k+2] - m);
        float e3 = ex2(S[jt][4*k+3] - m);
        S[jt][4*k+0]=e0; S[jt][4*k+1]=e1; S[jt][4*k+2]=e2; S[jt][4*k+3]=e3;
        t0 += e0; t1 += e1; t2 += e2; t3 += e3;
      }
      l += (t0 + t1) + (t2 + t3);
    }
    {
      unsigned lu = __builtin_bit_cast(unsigned, l);
      u32x2 ll = lswap(lu, lu);
      l = __builtin_bit_cast(float, ll[0]) + __builtin_bit_cast(float, ll[1]);
    }
    const float rl = 1.0f / l;
    // ---- PV: O^T[d][q] += Vt[d][j] * P^T[j][q]; P-frags via lswap.
    f32x16 o0 = z16(), o1 = z16();
#pragma unroll
    for (int jt = 0; jt < 10; ++jt){
      unsigned P0a = pkbf(S[jt][0], S[jt][1]),  P0b = pkbf(S[jt][2], S[jt][3]);
      unsigned P1a = pkbf(S[jt][4], S[jt][5]),  P1b = pkbf(S[jt][6], S[jt][7]);
      unsigned P2a = pkbf(S[jt][8], S[jt][9]),  P2b = pkbf(S[jt][10],S[jt][11]);
      unsigned P3a = pkbf(S[jt][12],S[jt][13]), P3b = pkbf(S[jt][14],S[jt][15]);
      u32x2 e0 = lswap(P0a,P1a), e1 = lswap(P0b,P1b);
      u32x2 d0 = lswap(P2a,P3a), d1 = lswap(P2b,P3b);
      u32x4 fe, fo;
      fe[0]=e0[0]; fe[1]=e1[0]; fe[2]=e0[1]; fe[3]=e1[1];
      fo[0]=d0[0]; fo[1]=d1[0]; fo[2]=d0[1]; fo[3]=d1[1];
      bf16x8 pe = __builtin_bit_cast(bf16x8, fe);
      bf16x8 po = __builtin_bit_cast(bf16x8, fo);
      bf16x8 va0e = *(const bf16x8*)(sm + VTOFF + (size_t)(     l31)*VTSTR + jt*64 + coff);
      bf16x8 va1e = *(const bf16x8*)(sm + VTOFF + (size_t)(32 + l31)*VTSTR + jt*64 + coff);
      bf16x8 va0o = *(const bf16x8*)(sm + VTOFF + (size_t)(     l31)*VTSTR + jt*64 + 32 + coff);
      bf16x8 va1o = *(const bf16x8*)(sm + VTOFF + (size_t)(32 + l31)*VTSTR + jt*64 + 32 + coff);
      __builtin_amdgcn_s_setprio(1);
      o0 = MFMA32(va0e, pe, o0);
      o1 = MFMA32(va1e, pe, o1);
      o0 = MFMA32(va0o, po, o0);
      o1 = MFMA32(va1o, po, o1);
      __builtin_amdgcn_s_setprio(0);
    }
    // ---- epilogue
    const size_t rowbase = (((size_t)i*NN) + q)*INNERD + h*DH;
#pragma unroll
    for (int rq = 0; rq < 4; ++rq){
      const int dd = 8*rq + 4*half;
      uint2 v0, v1;
      v0.x = pkbf(o0[4*rq+0]*rl, o0[4*rq+1]*rl); v0.y = pkbf(o0[4*rq+2]*rl, o0[4*rq+3]*rl);
      v1.x = pkbf(o1[4*rq+0]*rl, o1[4*rq+1]*rl); v1.y = pkbf(o1[4*rq+2]*rl, o1[4*rq+3]*rl);
      *(uint2*)(AttnOut + rowbase + dd)      = v0;
      *(uint2*)(AttnOut + rowbase + 32 + dd) = v1;
    }
  }
}

// ---------------------------------------------------------------------------
// proj: Out = Attn @ Wout + bout.  LDS = W^T only (67.6 KB -> 2 WG/CU).
// WT=true: stage from pre-transposed Woutt with coalesced u32x4 copies (all 256
// threads). WT=false: legacy strided-scalar transpose. A-frags from global;
// wave reads exactly the 32 rows it later overwrites (alias-safe in d_out).
// ---------------------------------------------------------------------------
#define B_WSTR 528
#define LDS_P  67584

template<bool WT>
__global__ void __launch_bounds__(256, 2) proj_kernel(const unsigned short* Attn,
                                                      const float* __restrict__ Wout,
                                                      const float* __restrict__ bout,
                                                      float* Out,
                                                      const unsigned short* __restrict__ Woutt){
  extern __shared__ char sm[];
  const int tid = threadIdx.x, w = tid>>6, lane = tid&63, half = lane>>5, l31 = lane&31;
  const int coff = half*16;
  const size_t r0 = (size_t)blockIdx.x * 128;
  if (WT){                                   // coalesced copy of pre-transposed W
    for (int idx = tid; idx < 128*32; idx += 256){
      const int col = idx >> 5, seg = idx & 31;
      u32x4 v = *(const u32x4*)(Woutt + (size_t)col*INNERD + seg*8);
      *(u32x4*)(sm + (size_t)col*B_WSTR + seg*16) = v;
    }
  } else if (tid < 128){                     // legacy on-the-fly transpose
    const int col = tid;
    char* dst = sm + (size_t)col*B_WSTR;
    for (int d0 = 0; d0 < 256; d0 += 8){
      u32x4 v;
      v[0] = pkbf(Wout[(size_t)(d0+0)*DIMD + col], Wout[(size_t)(d0+1)*DIMD + col]);
      v[1] = pkbf(Wout[(size_t)(d0+2)*DIMD + col], Wout[(size_t)(d0+3)*DIMD + col]);
      v[2] = pkbf(Wout[(size_t)(d0+4)*DIMD + col], Wout[(size_t)(d0+5)*DIMD + col]);
      v[3] = pkbf(Wout[(size_t)(d0+6)*DIMD + col], Wout[(size_t)(d0+7)*DIMD + col]);
      *(u32x4*)(dst + d0*2) = v;
    }
  }
  __syncthreads();
  f32x16 acc[4];
#pragma unroll
  for (int nt = 0; nt < 4; ++nt){
    float bv = bout[nt*32 + l31];
#pragma unroll
    for (int k = 0; k < 16; ++k) acc[nt][k] = bv;
  }
  const char* Ab = (const char*)Attn + (r0 + w*32 + l31)*512;
#pragma unroll
  for (int ks = 0; ks < 16; ++ks){
    bf16x8 a = *(const bf16x8*)(Ab + ks*32 + coff);
#pragma unroll
    for (int nt = 0; nt < 4; ++nt){
      bf16x8 b = *(const bf16x8*)(sm + (size_t)(nt*32 + l31)*B_WSTR + ks*32 + coff);
      acc[nt] = MFMA32(a, b, acc[nt]);
    }
  }
#pragma unroll
  for (int nt = 0; nt < 4; ++nt){
    const int c = nt*32 + l31;
#pragma unroll
    for (int rq = 0; rq < 4; ++rq){
#pragma unroll
      for (int r = 0; r < 4; ++r){
        const int rr = w*32 + 8*rq + 4*half + r;
        Out[(r0 + rr)*DIMD + c] = acc[nt][4*rq + r];
      }
    }
  }
}

// ---------------------------------------------------------------------------
extern "C" void kernel_launch(void* const* d_in, const int* in_sizes, int n_in,
                              void* d_out, int out_size, void* d_ws, size_t ws_size,
                              hipStream_t stream){
  const float* X     = (const float*)d_in[0];
  const float* Wqkv  = (const float*)d_in[1];
  const float* Wout  = (const float*)d_in[2];
  const float* bout  = (const float*)d_in[3];
  const float* Wbias = (const float*)d_in[4];
  float* Out = (float*)d_out;

  // ws layout: Bws fp32 [0,1638400) | Xbf bf16 [1638400,27852800)
  //            | Wqkvt [27852800,28049408) | Woutt [28049408,28114944)
  float*          Bws   = (float*)d_ws;
  unsigned short* Xbf   = (unsigned short*)((char*)d_ws + 1638400);
  unsigned*       XbfU  = (unsigned*)Xbf;
  unsigned short* Wqkvt = (unsigned short*)((char*)d_ws + 27852800);
  unsigned short* Woutt = (unsigned short*)((char*)d_ws + 28049408);
  const bool use_bf = (ws_size >= (size_t)28049408);
  const bool use_wt = (ws_size >= (size_t)28114944);

  unsigned short* Attn = (unsigned short*)d_out;   // bf16 intermediate lives in d_out

  if (use_bf){
    (void)hipFuncSetAttribute((const void*)attn_kernel<true>,
                              hipFuncAttributeMaxDynamicSharedMemorySize, LDS_A);
    x2bf_bias<true><<<NPAIR/16, 256, 0, stream>>>(X, Wbias, Bws, XbfU);
    wpack<<<use_wt ? 512 : 384, 256, 0, stream>>>(Wqkv, Wqkvt, Wout, Woutt);
    attn_kernel<true><<<dim3(NHEADS, NN), 512, LDS_A, stream>>>(X, Xbf, Wqkv, Wqkvt, Bws, Attn);
  } else {
    (void)hipFuncSetAttribute((const void*)attn_kernel<false>,
                              hipFuncAttributeMaxDynamicSharedMemorySize, LDS_A);
    x2bf_bias<false><<<NPAIR/16, 256, 0, stream>>>(X, Wbias, Bws, nullptr);
    attn_kernel<false><<<dim3(NHEADS, NN), 512, LDS_A, stream>>>(X, nullptr, Wqkv, nullptr, Bws, Attn);
  }
  if (use_wt){
    (void)hipFuncSetAttribute((const void*)proj_kernel<true>,
                              hipFuncAttributeMaxDynamicSharedMemorySize, LDS_P);
    proj_kernel<true><<<NPAIR/128, 256, LDS_P, stream>>>(Attn, Wout, bout, Out, Woutt);
  } else {
    (void)hipFuncSetAttribute((const void*)proj_kernel<false>,
                              hipFuncAttributeMaxDynamicSharedMemorySize, LDS_P);
    proj_kernel<false><<<NPAIR/128, 256, LDS_P, stream>>>(Attn, Wout, bout, Out, nullptr);
  }
}

// Round 9
// 275.042 us; speedup vs baseline: 1.4473x; 1.0840x over previous
//
#include <hip/hip_runtime.h>

// TriangleAttention (starting node), MI355X gfx950.  Round 10.
// B=1, N=320, DIM=128, HEADS=4, DH=64, INNER=256. fp32 I/O, bf16 MFMA inside.
//
// Round-10 = r9 + ONE attn-side change: bias layout.
//   OLD: Bws[h][q][j] fp32; attn phase-2 read float4 per (jt,rq,half) indexed by
//        per-lane q -> 32 lanes x 1280B-strided rows = 64 scattered 16B
//        transactions PER LOAD, 2560/task, 25600/block, on the softmax critical
//        path (attn is latency-bound: MfmaUtil 13 + VALU 27 => 60% dual-idle).
//   NEW: Bws[h][jg=j>>2][q][j&3] (float4 per (jg,q)). Lane load
//        Bq[(jt*8+2rq+half)*320 + q] -> consecutive lanes = consecutive float4,
//        fully coalesced (8 line-transactions/load, /8). Same element mapping.
//        x2bf gathers its 16 pair-results via 256B LDS and emits 16 coalesced
//        float4 writes/block (bias written once, read 320x -> move cost to write).
//   attn otherwise byte-identical to r8/r9 (permlane+exp2+setprio, 170us).

#define NN     320
#define DIMD   128
#define NHEADS 4
#define DH     64
#define INNERD 256
#define NPAIR  (NN*NN)
#define LOG2E  1.44269504f
#define SCL2   0.18033688f   // 0.125 * log2(e)

typedef __attribute__((ext_vector_type(8)))  short    bf16x8;
typedef __attribute__((ext_vector_type(16))) float    f32x16;
typedef __attribute__((ext_vector_type(4)))  unsigned u32x4;
typedef __attribute__((ext_vector_type(2)))  unsigned u32x2;

#define MFMA32(a,b,c) __builtin_amdgcn_mfma_f32_32x32x16_bf16((a),(b),(c),0,0,0)

#if defined(__has_builtin)
# if __has_builtin(__builtin_amdgcn_exp2f)
#  define HAVE_EXP2 1
# endif
# if __has_builtin(__builtin_amdgcn_permlane32_swap)
#  define HAVE_PLSWAP 1
# endif
#endif

// pack two f32 -> 2x bf16 (RTNE), proven bit-math version
__device__ __forceinline__ unsigned pkbf(float lo, float hi){
  unsigned a = __builtin_bit_cast(unsigned, lo);
  unsigned b = __builtin_bit_cast(unsigned, hi);
  a = (a + 0x7fffu + ((a>>16)&1u)) >> 16;
  b = (b + 0x7fffu + ((b>>16)&1u)) >> 16;
  return (a & 0xffffu) | (b<<16);
}
__device__ __forceinline__ unsigned short bf1(float f){
  unsigned u = __builtin_bit_cast(unsigned, f);
  return (unsigned short)((u + 0x7fffu + ((u>>16)&1u)) >> 16);
}
__device__ __forceinline__ float ex2(float x){
#ifdef HAVE_EXP2
  return __builtin_amdgcn_exp2f(x);
#else
  return exp2f(x);
#endif
}
// lane-half exchange: o[0] = {a.row0 | b.row0}, o[1] = {a.row1 | b.row1}
__device__ __forceinline__ u32x2 lswap(unsigned a, unsigned b){
#ifdef HAVE_PLSWAP
  auto r = __builtin_amdgcn_permlane32_swap((int)a, (int)b, false, false);
  u32x2 o; o[0] = (unsigned)r[0]; o[1] = (unsigned)r[1]; return o;
#else
  unsigned sa = __shfl_xor(a, 32), sb = __shfl_xor(b, 32);
  const bool hiHalf = (threadIdx.x & 32) != 0;
  u32x2 o; o[0] = hiHalf ? sb : a; o[1] = hiHalf ? b : sa; return o;
#endif
}
__device__ __forceinline__ f32x16 z16(){
  f32x16 v;
#pragma unroll
  for (int k = 0; k < 16; ++k) v[k] = 0.0f;
  return v;
}

// ---------------------------------------------------------------------------
// x2bf_bias: 16 lanes per pair, 16 pairs/block (6400 blocks). Bias written to
// TRANSPOSED j-grouped layout Bws[h][jg][q][4] via 256B LDS gather.
// Block handles pairs p = blk*16..+15: a = p/320 constant, b = b0..b0+15.
// Value for pair (a,b) is bias[h][q=a][j=b] -> Bws[h][b>>2][a][b&3].
// ---------------------------------------------------------------------------
template<bool XBF>
__global__ void __launch_bounds__(256) x2bf_bias(const float* __restrict__ X,
                                                 const float* __restrict__ Wbias,
                                                 float* __restrict__ Bws,
                                                 unsigned* __restrict__ XbfU){
  __shared__ float sb[16][4];
  const int tid = threadIdx.x;
  const int g   = tid >> 4;            // 0..15 : pair within block
  const int t16 = tid & 15;
  const int p   = blockIdx.x*16 + g;
  const float4* Xp = (const float4*)(X + (size_t)p*DIMD + t16*8);
  float4 x0 = Xp[0], x1 = Xp[1];
  const float4* Wb = (const float4*)Wbias;    // [128][4] fp32 rows
  float4 s = {0.f, 0.f, 0.f, 0.f};
  float xv[8] = {x0.x, x0.y, x0.z, x0.w, x1.x, x1.y, x1.z, x1.w};
#pragma unroll
  for (int j = 0; j < 8; ++j){
    float4 wj = Wb[t16*8 + j];
    s.x += xv[j]*wj.x;
    s.y += xv[j]*wj.y;
    s.z += xv[j]*wj.z;
    s.w += xv[j]*wj.w;
  }
  if (XBF){
    u32x4 v;
    v[0] = pkbf(x0.x, x0.y); v[1] = pkbf(x0.z, x0.w);
    v[2] = pkbf(x1.x, x1.y); v[3] = pkbf(x1.z, x1.w);
    *(u32x4*)(XbfU + (size_t)p*64 + t16*4) = v;
  }
#pragma unroll
  for (int off = 8; off >= 1; off >>= 1){
    s.x += __shfl_xor(s.x, off);
    s.y += __shfl_xor(s.y, off);
    s.z += __shfl_xor(s.z, off);
    s.w += __shfl_xor(s.w, off);
  }
  if (t16 == 0){
    sb[g][0] = s.x*LOG2E;
    sb[g][1] = s.y*LOG2E;
    sb[g][2] = s.z*LOG2E;
    sb[g][3] = s.w*LOG2E;
  }
  __syncthreads();
  if (tid < 16){
    const int jgl = tid >> 2, h = tid & 3;
    const int a  = (blockIdx.x*16) / NN;
    const int b0 = (blockIdx.x*16) % NN;     // 320%16==0 -> block stays in one row
    float4 v;
    v.x = sb[jgl*4+0][h];
    v.y = sb[jgl*4+1][h];
    v.z = sb[jgl*4+2][h];
    v.w = sb[jgl*4+3][h];
    ((float4*)(Bws + (size_t)h*NPAIR))[((b0>>2) + jgl)*NN + a] = v;
  }
}

// ---------------------------------------------------------------------------
// wpack: Wqkvt[c*128+d] = bf16(Wqkv[d*768+c])            (idx < 98304)
//        Woutt[c*256+d] = bf16(Wout[d*128+c])            (idx >= 98304, grid 512)
// ---------------------------------------------------------------------------
__global__ void __launch_bounds__(256) wpack(const float* __restrict__ Wqkv,
                                             unsigned short* __restrict__ Wqkvt,
                                             const float* __restrict__ Wout,
                                             unsigned short* __restrict__ Woutt){
  const int idx = blockIdx.x*256 + threadIdx.x;
  if (idx < 98304){
    const int c = idx % 768, d = idx / 768;
    Wqkvt[c*DIMD + d] = bf1(Wqkv[idx]);
  } else {
    const int i2 = idx - 98304;          // = d*128 + c, < 32768
    const int c = i2 & 127, d = i2 >> 7;
    Woutt[c*INNERD + d] = bf1(Wout[i2]);
  }
}

// ---------------------------------------------------------------------------
// attn kernel.  LDS map (bytes):
//   K   [320 j][64 d]  stride 144 :      0 ..  46080
//   Vt  [64 d][320 j]  stride 656 :  46080 ..  88064
//   W   [192 col][128 din] str 272:  88064 .. 140288   (q:0-63, k:64-127, v:128-191)
// ---------------------------------------------------------------------------
#define KOFF   0
#define VTOFF  46080
#define WOFF   88064
#define LDS_A  140288
#define KSTR   144
#define VTSTR  656
#define WSTR   272

template<bool XBF>
__device__ __forceinline__ bf16x8 xfrag(const float* Xf, const unsigned short* Xb,
                                        int row, int ks, int coff, int half){
  if constexpr (XBF){
    return *(const bf16x8*)((const char*)Xb + (size_t)row*256 + ks*32 + coff);
  } else {
    const float* p = Xf + (size_t)row*DIMD + ks*16 + half*8;
    float4 x0 = ((const float4*)p)[0], x1 = ((const float4*)p)[1];
    u32x4 v; v[0]=pkbf(x0.x,x0.y); v[1]=pkbf(x0.z,x0.w); v[2]=pkbf(x1.x,x1.y); v[3]=pkbf(x1.z,x1.w);
    return __builtin_bit_cast(bf16x8, v);
  }
}

template<bool XBF>
__global__ void __launch_bounds__(512, 2) attn_kernel(const float* __restrict__ X,
                                                      const unsigned short* __restrict__ Xbf,
                                                      const float* __restrict__ Wqkv,
                                                      const unsigned short* __restrict__ Wqkvt,
                                                      const float* __restrict__ Bws,
                                                      unsigned short* __restrict__ AttnOut){
  extern __shared__ char sm[];
  const int h = blockIdx.x, i = blockIdx.y;
  const int tid  = threadIdx.x;
  const int w    = tid >> 6;
  const int lane = tid & 63;
  const int half = lane >> 5;
  const int l31  = lane & 31;
  const int coff = half*16;

  // ---- stage W (q|k|v cols for this head), transposed [col][din] bf16
  if (XBF){
    for (int idx = tid; idx < 192*16; idx += 512){
      const int col = idx >> 4, seg = idx & 15;
      const int gcol = (col < 64)  ? (h*DH + col)
                     : (col < 128) ? (INNERD   + h*DH + (col-64))
                                   : (2*INNERD + h*DH + (col-128));
      u32x4 v = *(const u32x4*)(Wqkvt + (size_t)gcol*DIMD + seg*8);
      *(u32x4*)(sm + WOFF + (size_t)col*WSTR + seg*16) = v;
    }
  } else if (tid < 192){
    const int col  = tid;
    const int gcol = (col < 64)  ? (h*DH + col)
                   : (col < 128) ? (INNERD   + h*DH + (col-64))
                                 : (2*INNERD + h*DH + (col-128));
    char* dst = sm + WOFF + (size_t)col*WSTR;
    for (int d0 = 0; d0 < DIMD; d0 += 8){
      u32x4 v;
      v[0] = pkbf(Wqkv[(size_t)(d0+0)*768 + gcol], Wqkv[(size_t)(d0+1)*768 + gcol]);
      v[1] = pkbf(Wqkv[(size_t)(d0+2)*768 + gcol], Wqkv[(size_t)(d0+3)*768 + gcol]);
      v[2] = pkbf(Wqkv[(size_t)(d0+4)*768 + gcol], Wqkv[(size_t)(d0+5)*768 + gcol]);
      v[3] = pkbf(Wqkv[(size_t)(d0+6)*768 + gcol], Wqkv[(size_t)(d0+7)*768 + gcol]);
      *(u32x4*)(dst + d0*2) = v;
    }
  }
  __syncthreads();

  // ================= phase 1: 20 barrier-free wave-tasks (10 K, 10 V) ==========
  for (int r = 0; r < 3; ++r){
    const int t = w + 8*r;
    if (t >= 20) break;
    const bool isK = (t < 10);
    const int  jt  = isK ? t : t - 10;
    const int  jrow = jt*32 + l31;
    const int  grow = i*NN + jrow;
    f32x16 acc0 = z16(), acc1 = z16();
    if (isK){
      const char* A0 = sm + WOFF + (size_t)(64 + l31)*WSTR;
      const char* A1 = sm + WOFF + (size_t)(96 + l31)*WSTR;
#pragma unroll
      for (int ks = 0; ks < 8; ++ks){
        bf16x8 b  = xfrag<XBF>(X, Xbf, grow, ks, coff, half);
        bf16x8 a0 = *(const bf16x8*)(A0 + ks*32 + coff);
        bf16x8 a1 = *(const bf16x8*)(A1 + ks*32 + coff);
        acc0 = MFMA32(a0, b, acc0);
        acc1 = MFMA32(a1, b, acc1);
      }
#pragma unroll
      for (int rq = 0; rq < 4; ++rq){
        uint2 v0, v1;
        v0.x = pkbf(acc0[4*rq+0], acc0[4*rq+1]); v0.y = pkbf(acc0[4*rq+2], acc0[4*rq+3]);
        v1.x = pkbf(acc1[4*rq+0], acc1[4*rq+1]); v1.y = pkbf(acc1[4*rq+2], acc1[4*rq+3]);
        *(uint2*)(sm + KOFF + (size_t)jrow*KSTR +      (8*rq + 4*half)*2) = v0;
        *(uint2*)(sm + KOFF + (size_t)jrow*KSTR + 64 + (8*rq + 4*half)*2) = v1;
      }
    } else {
      const char* B0 = sm + WOFF + (size_t)(128 + l31)*WSTR;
      const char* B1 = sm + WOFF + (size_t)(160 + l31)*WSTR;
#pragma unroll
      for (int ks = 0; ks < 8; ++ks){
        bf16x8 a  = xfrag<XBF>(X, Xbf, grow, ks, coff, half);
        bf16x8 b0 = *(const bf16x8*)(B0 + ks*32 + coff);
        bf16x8 b1 = *(const bf16x8*)(B1 + ks*32 + coff);
        acc0 = MFMA32(a, b0, acc0);
        acc1 = MFMA32(a, b1, acc1);
      }
#pragma unroll
      for (int rq = 0; rq < 4; ++rq){
        uint2 v0, v1;
        v0.x = pkbf(acc0[4*rq+0], acc0[4*rq+1]); v0.y = pkbf(acc0[4*rq+2], acc0[4*rq+3]);
        v1.x = pkbf(acc1[4*rq+0], acc1[4*rq+1]); v1.y = pkbf(acc1[4*rq+2], acc1[4*rq+3]);
        *(uint2*)(sm + VTOFF + (size_t)(     l31)*VTSTR + (jt*32 + 8*rq + 4*half)*2) = v0;
        *(uint2*)(sm + VTOFF + (size_t)(32 + l31)*VTSTR + (jt*32 + 8*rq + 4*half)*2) = v1;
      }
    }
  }
  __syncthreads();

  // ================= phase 2: 10 q-tile wave-tasks over 8 waves ===============
  for (int rep = 0; rep < 2; ++rep){
    const int qt = w + 8*rep;
    if (qt >= 10) break;
    const int q = qt*32 + l31;
    // ---- Q-proj: D col = q, rows = d
    f32x16 qa0 = z16(), qa1 = z16();
#pragma unroll
    for (int ks = 0; ks < 8; ++ks){
      bf16x8 b  = xfrag<XBF>(X, Xbf, i*NN + q, ks, coff, half);
      bf16x8 a0 = *(const bf16x8*)(sm + WOFF + (size_t)(     l31)*WSTR + ks*32 + coff);
      bf16x8 a1 = *(const bf16x8*)(sm + WOFF + (size_t)(32 + l31)*WSTR + ks*32 + coff);
      qa0 = MFMA32(a0, b, qa0);
      qa1 = MFMA32(a1, b, qa1);
    }
    // ---- build qf[4] (B-frags over d) in-register from D-layout via lswap
    bf16x8 qf[4];
    {
      unsigned a0 = pkbf(qa0[0],qa0[1]),  a0b = pkbf(qa0[2],qa0[3]);
      unsigned a1 = pkbf(qa0[4],qa0[5]),  a1b = pkbf(qa0[6],qa0[7]);
      unsigned a2 = pkbf(qa0[8],qa0[9]),  a2b = pkbf(qa0[10],qa0[11]);
      unsigned a3 = pkbf(qa0[12],qa0[13]),a3b = pkbf(qa0[14],qa0[15]);
      unsigned b0 = pkbf(qa1[0],qa1[1]),  b0b = pkbf(qa1[2],qa1[3]);
      unsigned b1 = pkbf(qa1[4],qa1[5]),  b1b = pkbf(qa1[6],qa1[7]);
      unsigned b2 = pkbf(qa1[8],qa1[9]),  b2b = pkbf(qa1[10],qa1[11]);
      unsigned b3 = pkbf(qa1[12],qa1[13]),b3b = pkbf(qa1[14],qa1[15]);
      u32x2 s0 = lswap(a0,a1), s0b = lswap(a0b,a1b);
      u32x2 s1 = lswap(a2,a3), s1b = lswap(a2b,a3b);
      u32x2 s2 = lswap(b0,b1), s2b = lswap(b0b,b1b);
      u32x2 s3 = lswap(b2,b3), s3b = lswap(b2b,b3b);
      u32x4 f;
      f[0]=s0[0]; f[1]=s0b[0]; f[2]=s0[1]; f[3]=s0b[1]; qf[0]=__builtin_bit_cast(bf16x8,f);
      f[0]=s1[0]; f[1]=s1b[0]; f[2]=s1[1]; f[3]=s1b[1]; qf[1]=__builtin_bit_cast(bf16x8,f);
      f[0]=s2[0]; f[1]=s2b[0]; f[2]=s2[1]; f[3]=s2b[1]; qf[2]=__builtin_bit_cast(bf16x8,f);
      f[0]=s3[0]; f[1]=s3b[0]; f[2]=s3[1]; f[3]=s3b[1]; qf[3]=__builtin_bit_cast(bf16x8,f);
    }
    // ---- scores^T: S[j][q], D col = q = l31, rows = j
    f32x16 S[10];
#pragma unroll
    for (int jt = 0; jt < 10; ++jt) S[jt] = z16();
    __builtin_amdgcn_s_setprio(1);
#pragma unroll
    for (int jt = 0; jt < 10; ++jt){
#pragma unroll
      for (int c = 0; c < 4; ++c){
        bf16x8 a = *(const bf16x8*)(sm + KOFF + (size_t)(jt*32 + l31)*KSTR + c*32 + coff);
        S[jt] = MFMA32(a, qf[c], S[jt]);
      }
    }
    __builtin_amdgcn_s_setprio(0);
    // ---- scale + bias (coalesced j-grouped layout) + softmax over j
    const float4* Bq = (const float4*)(Bws + (size_t)h*NPAIR);
    float m = -3.0e38f;
#pragma unroll
    for (int jt = 0; jt < 10; ++jt){
      float mj = -3.0e38f;
#pragma unroll
      for (int rq = 0; rq < 4; ++rq){
        float4 bv = Bq[(jt*8 + 2*rq + half)*NN + q];
        float v0 = S[jt][4*rq+0]*SCL2 + bv.x;
        float v1 = S[jt][4*rq+1]*SCL2 + bv.y;
        float v2 = S[jt][4*rq+2]*SCL2 + bv.z;
        float v3 = S[jt][4*rq+3]*SCL2 + bv.w;
        S[jt][4*rq+0]=v0; S[jt][4*rq+1]=v1; S[jt][4*rq+2]=v2; S[jt][4*rq+3]=v3;
        mj = fmaxf(mj, fmaxf(fmaxf(v0,v1), fmaxf(v2,v3)));
      }
      m = fmaxf(m, mj);
    }
    {
      unsigned mu = __builtin_bit_cast(unsigned, m);
      u32x2 mm = lswap(mu, mu);
      m = fmaxf(__builtin_bit_cast(float, mm[0]), __builtin_bit_cast(float, mm[1]));
    }
    float l = 0.0f;
#pragma unroll
    for (int jt = 0; jt < 10; ++jt){
      float t0 = 0.f, t1 = 0.f, t2 = 0.f, t3 = 0.f;
#pragma unroll
      for (int k = 0; k < 4; ++k){
        float e0 = ex2(S[jt][4*k+0] - m);
        float e1 = ex2(S[jt][4*k+1] - m);
        float e2 = ex2(S[jt][4*k+2] - m);
        float e3 = ex2(S[jt][4*k+3] - m);
        S[jt][4*k+0]=e0; S[jt][4*k+1]=e1; S[jt][4*k+2]=e2; S[jt][4*k+3]=e3;
        t0 += e0; t1 += e1; t2 += e2; t3 += e3;
      }
      l += (t0 + t1) + (t2 + t3);
    }
    {
      unsigned lu = __builtin_bit_cast(unsigned, l);
      u32x2 ll = lswap(lu, lu);
      l = __builtin_bit_cast(float, ll[0]) + __builtin_bit_cast(float, ll[1]);
    }
    const float rl = 1.0f / l;
    // ---- PV: O^T[d][q] += Vt[d][j] * P^T[j][q]; P-frags via lswap.
    f32x16 o0 = z16(), o1 = z16();
#pragma unroll
    for (int jt = 0; jt < 10; ++jt){
      unsigned P0a = pkbf(S[jt][0], S[jt][1]),  P0b = pkbf(S[jt][2], S[jt][3]);
      unsigned P1a = pkbf(S[jt][4], S[jt][5]),  P1b = pkbf(S[jt][6], S[jt][7]);
      unsigned P2a = pkbf(S[jt][8], S[jt][9]),  P2b = pkbf(S[jt][10],S[jt][11]);
      unsigned P3a = pkbf(S[jt][12],S[jt][13]), P3b = pkbf(S[jt][14],S[jt][15]);
      u32x2 e0 = lswap(P0a,P1a), e1 = lswap(P0b,P1b);
      u32x2 d0 = lswap(P2a,P3a), d1 = lswap(P2b,P3b);
      u32x4 fe, fo;
      fe[0]=e0[0]; fe[1]=e1[0]; fe[2]=e0[1]; fe[3]=e1[1];
      fo[0]=d0[0]; fo[1]=d1[0]; fo[2]=d0[1]; fo[3]=d1[1];
      bf16x8 pe = __builtin_bit_cast(bf16x8, fe);
      bf16x8 po = __builtin_bit_cast(bf16x8, fo);
      bf16x8 va0e = *(const bf16x8*)(sm + VTOFF + (size_t)(     l31)*VTSTR + jt*64 + coff);
      bf16x8 va1e = *(const bf16x8*)(sm + VTOFF + (size_t)(32 + l31)*VTSTR + jt*64 + coff);
      bf16x8 va0o = *(const bf16x8*)(sm + VTOFF + (size_t)(     l31)*VTSTR + jt*64 + 32 + coff);
      bf16x8 va1o = *(const bf16x8*)(sm + VTOFF + (size_t)(32 + l31)*VTSTR + jt*64 + 32 + coff);
      __builtin_amdgcn_s_setprio(1);
      o0 = MFMA32(va0e, pe, o0);
      o1 = MFMA32(va1e, pe, o1);
      o0 = MFMA32(va0o, po, o0);
      o1 = MFMA32(va1o, po, o1);
      __builtin_amdgcn_s_setprio(0);
    }
    // ---- epilogue
    const size_t rowbase = (((size_t)i*NN) + q)*INNERD + h*DH;
#pragma unroll
    for (int rq = 0; rq < 4; ++rq){
      const int dd = 8*rq + 4*half;
      uint2 v0, v1;
      v0.x = pkbf(o0[4*rq+0]*rl, o0[4*rq+1]*rl); v0.y = pkbf(o0[4*rq+2]*rl, o0[4*rq+3]*rl);
      v1.x = pkbf(o1[4*rq+0]*rl, o1[4*rq+1]*rl); v1.y = pkbf(o1[4*rq+2]*rl, o1[4*rq+3]*rl);
      *(uint2*)(AttnOut + rowbase + dd)      = v0;
      *(uint2*)(AttnOut + rowbase + 32 + dd) = v1;
    }
  }
}

// ---------------------------------------------------------------------------
// proj: Out = Attn @ Wout + bout.  LDS = W^T only (67.6 KB -> 2 WG/CU).
// WT=true: stage from pre-transposed Woutt with coalesced u32x4 copies.
// ---------------------------------------------------------------------------
#define B_WSTR 528
#define LDS_P  67584

template<bool WT>
__global__ void __launch_bounds__(256, 2) proj_kernel(const unsigned short* Attn,
                                                      const float* __restrict__ Wout,
                                                      const float* __restrict__ bout,
                                                      float* Out,
                                                      const unsigned short* __restrict__ Woutt){
  extern __shared__ char sm[];
  const int tid = threadIdx.x, w = tid>>6, lane = tid&63, half = lane>>5, l31 = lane&31;
  const int coff = half*16;
  const size_t r0 = (size_t)blockIdx.x * 128;
  if (WT){                                   // coalesced copy of pre-transposed W
    for (int idx = tid; idx < 128*32; idx += 256){
      const int col = idx >> 5, seg = idx & 31;
      u32x4 v = *(const u32x4*)(Woutt + (size_t)col*INNERD + seg*8);
      *(u32x4*)(sm + (size_t)col*B_WSTR + seg*16) = v;
    }
  } else if (tid < 128){                     // legacy on-the-fly transpose
    const int col = tid;
    char* dst = sm + (size_t)col*B_WSTR;
    for (int d0 = 0; d0 < 256; d0 += 8){
      u32x4 v;
      v[0] = pkbf(Wout[(size_t)(d0+0)*DIMD + col], Wout[(size_t)(d0+1)*DIMD + col]);
      v[1] = pkbf(Wout[(size_t)(d0+2)*DIMD + col], Wout[(size_t)(d0+3)*DIMD + col]);
      v[2] = pkbf(Wout[(size_t)(d0+4)*DIMD + col], Wout[(size_t)(d0+5)*DIMD + col]);
      v[3] = pkbf(Wout[(size_t)(d0+6)*DIMD + col], Wout[(size_t)(d0+7)*DIMD + col]);
      *(u32x4*)(dst + d0*2) = v;
    }
  }
  __syncthreads();
  f32x16 acc[4];
#pragma unroll
  for (int nt = 0; nt < 4; ++nt){
    float bv = bout[nt*32 + l31];
#pragma unroll
    for (int k = 0; k < 16; ++k) acc[nt][k] = bv;
  }
  const char* Ab = (const char*)Attn + (r0 + w*32 + l31)*512;
#pragma unroll
  for (int ks = 0; ks < 16; ++ks){
    bf16x8 a = *(const bf16x8*)(Ab + ks*32 + coff);
#pragma unroll
    for (int nt = 0; nt < 4; ++nt){
      bf16x8 b = *(const bf16x8*)(sm + (size_t)(nt*32 + l31)*B_WSTR + ks*32 + coff);
      acc[nt] = MFMA32(a, b, acc[nt]);
    }
  }
#pragma unroll
  for (int nt = 0; nt < 4; ++nt){
    const int c = nt*32 + l31;
#pragma unroll
    for (int rq = 0; rq < 4; ++rq){
#pragma unroll
      for (int r = 0; r < 4; ++r){
        const int rr = w*32 + 8*rq + 4*half + r;
        Out[(r0 + rr)*DIMD + c] = acc[nt][4*rq + r];
      }
    }
  }
}

// ---------------------------------------------------------------------------
extern "C" void kernel_launch(void* const* d_in, const int* in_sizes, int n_in,
                              void* d_out, int out_size, void* d_ws, size_t ws_size,
                              hipStream_t stream){
  const float* X     = (const float*)d_in[0];
  const float* Wqkv  = (const float*)d_in[1];
  const float* Wout  = (const float*)d_in[2];
  const float* bout  = (const float*)d_in[3];
  const float* Wbias = (const float*)d_in[4];
  float* Out = (float*)d_out;

  // ws layout: Bws fp32 [0,1638400) | Xbf bf16 [1638400,27852800)
  //            | Wqkvt [27852800,28049408) | Woutt [28049408,28114944)
  float*          Bws   = (float*)d_ws;
  unsigned short* Xbf   = (unsigned short*)((char*)d_ws + 1638400);
  unsigned*       XbfU  = (unsigned*)Xbf;
  unsigned short* Wqkvt = (unsigned short*)((char*)d_ws + 27852800);
  unsigned short* Woutt = (unsigned short*)((char*)d_ws + 28049408);
  const bool use_bf = (ws_size >= (size_t)28049408);
  const bool use_wt = (ws_size >= (size_t)28114944);

  unsigned short* Attn = (unsigned short*)d_out;   // bf16 intermediate lives in d_out

  if (use_bf){
    (void)hipFuncSetAttribute((const void*)attn_kernel<true>,
                              hipFuncAttributeMaxDynamicSharedMemorySize, LDS_A);
    x2bf_bias<true><<<NPAIR/16, 256, 0, stream>>>(X, Wbias, Bws, XbfU);
    wpack<<<use_wt ? 512 : 384, 256, 0, stream>>>(Wqkv, Wqkvt, Wout, Woutt);
    attn_kernel<true><<<dim3(NHEADS, NN), 512, LDS_A, stream>>>(X, Xbf, Wqkv, Wqkvt, Bws, Attn);
  } else {
    (void)hipFuncSetAttribute((const void*)attn_kernel<false>,
                              hipFuncAttributeMaxDynamicSharedMemorySize, LDS_A);
    x2bf_bias<false><<<NPAIR/16, 256, 0, stream>>>(X, Wbias, Bws, nullptr);
    attn_kernel<false><<<dim3(NHEADS, NN), 512, LDS_A, stream>>>(X, nullptr, Wqkv, nullptr, Bws, Attn);
  }
  if (use_wt){
    (void)hipFuncSetAttribute((const void*)proj_kernel<true>,
                              hipFuncAttributeMaxDynamicSharedMemorySize, LDS_P);
    proj_kernel<true><<<NPAIR/128, 256, LDS_P, stream>>>(Attn, Wout, bout, Out, Woutt);
  } else {
    (void)hipFuncSetAttribute((const void*)proj_kernel<false>,
                              hipFuncAttributeMaxDynamicSharedMemorySize, LDS_P);
    proj_kernel<false><<<NPAIR/128, 256, LDS_P, stream>>>(Attn, Wout, bout, Out, nullptr);
  }
}

// Round 10
// 258.639 us; speedup vs baseline: 1.5391x; 1.0634x over previous
//
#include <hip/hip_runtime.h>

// TriangleAttention (starting node), MI355X gfx950.  Round 11.
// B=1, N=320, DIM=128, HEADS=4, DH=64, INNER=256. fp32 I/O, bf16 MFMA inside.
//
// Round-11 = r10 + blocked 32-row layouts for the two remaining scatter streams
// (same trick as r10's bias fix, which gave -23us):
//  * Xbf2[rowblk=row/32][u=col/8][row%32] 16B units: attn xfrag loads become
//    contiguous 512B wave-reads (were 64x16B at 256B stride, ~240 loads/block).
//    x2bf writes 64B chunks (26MB once; read 320x coalesced).
//  * Attn2 intermediate same blocked layout: attn epilogue = full 512B
//    wave-stores (lanes 0-31 fill bytes 0-7, 32-63 fill 8-15 of each unit);
//    proj A-frags read contiguous. Wave reads/writes its own 32 rows -> the
//    d_out aliasing (read-before-overwrite) stays per-wave safe.
//  * everything else byte-identical to r10 (permlane+exp2+setprio attn 147us,
//    j-grouped bias, Woutt pre-transpose).

#define NN     320
#define DIMD   128
#define NHEADS 4
#define DH     64
#define INNERD 256
#define NPAIR  (NN*NN)
#define LOG2E  1.44269504f
#define SCL2   0.18033688f   // 0.125 * log2(e)

typedef __attribute__((ext_vector_type(8)))  short    bf16x8;
typedef __attribute__((ext_vector_type(16))) float    f32x16;
typedef __attribute__((ext_vector_type(4)))  unsigned u32x4;
typedef __attribute__((ext_vector_type(2)))  unsigned u32x2;

#define MFMA32(a,b,c) __builtin_amdgcn_mfma_f32_32x32x16_bf16((a),(b),(c),0,0,0)

#if defined(__has_builtin)
# if __has_builtin(__builtin_amdgcn_exp2f)
#  define HAVE_EXP2 1
# endif
# if __has_builtin(__builtin_amdgcn_permlane32_swap)
#  define HAVE_PLSWAP 1
# endif
#endif

// pack two f32 -> 2x bf16 (RTNE), proven bit-math version
__device__ __forceinline__ unsigned pkbf(float lo, float hi){
  unsigned a = __builtin_bit_cast(unsigned, lo);
  unsigned b = __builtin_bit_cast(unsigned, hi);
  a = (a + 0x7fffu + ((a>>16)&1u)) >> 16;
  b = (b + 0x7fffu + ((b>>16)&1u)) >> 16;
  return (a & 0xffffu) | (b<<16);
}
__device__ __forceinline__ unsigned short bf1(float f){
  unsigned u = __builtin_bit_cast(unsigned, f);
  return (unsigned short)((u + 0x7fffu + ((u>>16)&1u)) >> 16);
}
__device__ __forceinline__ float ex2(float x){
#ifdef HAVE_EXP2
  return __builtin_amdgcn_exp2f(x);
#else
  return exp2f(x);
#endif
}
// lane-half exchange: o[0] = {a.row0 | b.row0}, o[1] = {a.row1 | b.row1}
__device__ __forceinline__ u32x2 lswap(unsigned a, unsigned b){
#ifdef HAVE_PLSWAP
  auto r = __builtin_amdgcn_permlane32_swap((int)a, (int)b, false, false);
  u32x2 o; o[0] = (unsigned)r[0]; o[1] = (unsigned)r[1]; return o;
#else
  unsigned sa = __shfl_xor(a, 32), sb = __shfl_xor(b, 32);
  const bool hiHalf = (threadIdx.x & 32) != 0;
  u32x2 o; o[0] = hiHalf ? sb : a; o[1] = hiHalf ? b : sa; return o;
#endif
}
__device__ __forceinline__ f32x16 z16(){
  f32x16 v;
#pragma unroll
  for (int k = 0; k < 16; ++k) v[k] = 0.0f;
  return v;
}

// ---------------------------------------------------------------------------
// x2bf_bias: 16 lanes per pair, 16 pairs/block (6400 blocks).
// Xbf written in BLOCKED layout: unit (rowblk=p/32, u=t16, l=p%32), 16B each.
// Bias written to transposed j-grouped layout Bws[h][jg][q][4] via LDS gather.
// ---------------------------------------------------------------------------
template<bool XBF>
__global__ void __launch_bounds__(256) x2bf_bias(const float* __restrict__ X,
                                                 const float* __restrict__ Wbias,
                                                 float* __restrict__ Bws,
                                                 unsigned* __restrict__ XbfU){
  __shared__ float sb[16][4];
  const int tid = threadIdx.x;
  const int g   = tid >> 4;            // 0..15 : pair within block
  const int t16 = tid & 15;
  const int p   = blockIdx.x*16 + g;
  const float4* Xp = (const float4*)(X + (size_t)p*DIMD + t16*8);
  float4 x0 = Xp[0], x1 = Xp[1];
  const float4* Wb = (const float4*)Wbias;    // [128][4] fp32 rows
  float4 s = {0.f, 0.f, 0.f, 0.f};
  float xv[8] = {x0.x, x0.y, x0.z, x0.w, x1.x, x1.y, x1.z, x1.w};
#pragma unroll
  for (int j = 0; j < 8; ++j){
    float4 wj = Wb[t16*8 + j];
    s.x += xv[j]*wj.x;
    s.y += xv[j]*wj.y;
    s.z += xv[j]*wj.z;
    s.w += xv[j]*wj.w;
  }
  if (XBF){
    u32x4 v;
    v[0] = pkbf(x0.x, x0.y); v[1] = pkbf(x0.z, x0.w);
    v[2] = pkbf(x1.x, x1.y); v[3] = pkbf(x1.z, x1.w);
    const size_t unit = ((size_t)(p >> 5)*16 + t16)*32 + (p & 31);
    *(u32x4*)(XbfU + unit*4) = v;
  }
#pragma unroll
  for (int off = 8; off >= 1; off >>= 1){
    s.x += __shfl_xor(s.x, off);
    s.y += __shfl_xor(s.y, off);
    s.z += __shfl_xor(s.z, off);
    s.w += __shfl_xor(s.w, off);
  }
  if (t16 == 0){
    sb[g][0] = s.x*LOG2E;
    sb[g][1] = s.y*LOG2E;
    sb[g][2] = s.z*LOG2E;
    sb[g][3] = s.w*LOG2E;
  }
  __syncthreads();
  if (tid < 16){
    const int jgl = tid >> 2, h = tid & 3;
    const int a  = (blockIdx.x*16) / NN;
    const int b0 = (blockIdx.x*16) % NN;     // 320%16==0 -> block stays in one row
    float4 v;
    v.x = sb[jgl*4+0][h];
    v.y = sb[jgl*4+1][h];
    v.z = sb[jgl*4+2][h];
    v.w = sb[jgl*4+3][h];
    ((float4*)(Bws + (size_t)h*NPAIR))[((b0>>2) + jgl)*NN + a] = v;
  }
}

// ---------------------------------------------------------------------------
// wpack: Wqkvt[c*128+d] = bf16(Wqkv[d*768+c])            (idx < 98304)
//        Woutt[c*256+d] = bf16(Wout[d*128+c])            (idx >= 98304, grid 512)
// ---------------------------------------------------------------------------
__global__ void __launch_bounds__(256) wpack(const float* __restrict__ Wqkv,
                                             unsigned short* __restrict__ Wqkvt,
                                             const float* __restrict__ Wout,
                                             unsigned short* __restrict__ Woutt){
  const int idx = blockIdx.x*256 + threadIdx.x;
  if (idx < 98304){
    const int c = idx % 768, d = idx / 768;
    Wqkvt[c*DIMD + d] = bf1(Wqkv[idx]);
  } else {
    const int i2 = idx - 98304;          // = d*128 + c, < 32768
    const int c = i2 & 127, d = i2 >> 7;
    Woutt[c*INNERD + d] = bf1(Wout[i2]);
  }
}

// ---------------------------------------------------------------------------
// attn kernel.  LDS map (bytes):
//   K   [320 j][64 d]  stride 144 :      0 ..  46080
//   Vt  [64 d][320 j]  stride 656 :  46080 ..  88064
//   W   [192 col][128 din] str 272:  88064 .. 140288   (q:0-63, k:64-127, v:128-191)
// ---------------------------------------------------------------------------
#define KOFF   0
#define VTOFF  46080
#define WOFF   88064
#define LDS_A  140288
#define KSTR   144
#define VTSTR  656
#define WSTR   272

// Xbf blocked-layout fragment read: contiguous 512B per wave (row = base+l31).
template<bool XBF>
__device__ __forceinline__ bf16x8 xfrag(const float* Xf, const unsigned short* Xb,
                                        int row, int ks, int coff, int half){
  if constexpr (XBF){
    const size_t unit = ((size_t)(row >> 5)*16 + ks*2 + half)*32 + (row & 31);
    return *(const bf16x8*)((const char*)Xb + unit*16);
  } else {
    const float* p = Xf + (size_t)row*DIMD + ks*16 + half*8;
    float4 x0 = ((const float4*)p)[0], x1 = ((const float4*)p)[1];
    u32x4 v; v[0]=pkbf(x0.x,x0.y); v[1]=pkbf(x0.z,x0.w); v[2]=pkbf(x1.x,x1.y); v[3]=pkbf(x1.z,x1.w);
    return __builtin_bit_cast(bf16x8, v);
  }
}

template<bool XBF>
__global__ void __launch_bounds__(512, 2) attn_kernel(const float* __restrict__ X,
                                                      const unsigned short* __restrict__ Xbf,
                                                      const float* __restrict__ Wqkv,
                                                      const unsigned short* __restrict__ Wqkvt,
                                                      const float* __restrict__ Bws,
                                                      unsigned short* __restrict__ AttnOut){
  extern __shared__ char sm[];
  const int h = blockIdx.x, i = blockIdx.y;
  const int tid  = threadIdx.x;
  const int w    = tid >> 6;
  const int lane = tid & 63;
  const int half = lane >> 5;
  const int l31  = lane & 31;
  const int coff = half*16;

  // ---- stage W (q|k|v cols for this head), transposed [col][din] bf16
  if (XBF){
    for (int idx = tid; idx < 192*16; idx += 512){
      const int col = idx >> 4, seg = idx & 15;
      const int gcol = (col < 64)  ? (h*DH + col)
                     : (col < 128) ? (INNERD   + h*DH + (col-64))
                                   : (2*INNERD + h*DH + (col-128));
      u32x4 v = *(const u32x4*)(Wqkvt + (size_t)gcol*DIMD + seg*8);
      *(u32x4*)(sm + WOFF + (size_t)col*WSTR + seg*16) = v;
    }
  } else if (tid < 192){
    const int col  = tid;
    const int gcol = (col < 64)  ? (h*DH + col)
                   : (col < 128) ? (INNERD   + h*DH + (col-64))
                                 : (2*INNERD + h*DH + (col-128));
    char* dst = sm + WOFF + (size_t)col*WSTR;
    for (int d0 = 0; d0 < DIMD; d0 += 8){
      u32x4 v;
      v[0] = pkbf(Wqkv[(size_t)(d0+0)*768 + gcol], Wqkv[(size_t)(d0+1)*768 + gcol]);
      v[1] = pkbf(Wqkv[(size_t)(d0+2)*768 + gcol], Wqkv[(size_t)(d0+3)*768 + gcol]);
      v[2] = pkbf(Wqkv[(size_t)(d0+4)*768 + gcol], Wqkv[(size_t)(d0+5)*768 + gcol]);
      v[3] = pkbf(Wqkv[(size_t)(d0+6)*768 + gcol], Wqkv[(size_t)(d0+7)*768 + gcol]);
      *(u32x4*)(dst + d0*2) = v;
    }
  }
  __syncthreads();

  // ================= phase 1: 20 barrier-free wave-tasks (10 K, 10 V) ==========
  for (int r = 0; r < 3; ++r){
    const int t = w + 8*r;
    if (t >= 20) break;
    const bool isK = (t < 10);
    const int  jt  = isK ? t : t - 10;
    const int  jrow = jt*32 + l31;
    const int  grow = i*NN + jrow;
    f32x16 acc0 = z16(), acc1 = z16();
    if (isK){
      const char* A0 = sm + WOFF + (size_t)(64 + l31)*WSTR;
      const char* A1 = sm + WOFF + (size_t)(96 + l31)*WSTR;
#pragma unroll
      for (int ks = 0; ks < 8; ++ks){
        bf16x8 b  = xfrag<XBF>(X, Xbf, grow, ks, coff, half);
        bf16x8 a0 = *(const bf16x8*)(A0 + ks*32 + coff);
        bf16x8 a1 = *(const bf16x8*)(A1 + ks*32 + coff);
        acc0 = MFMA32(a0, b, acc0);
        acc1 = MFMA32(a1, b, acc1);
      }
#pragma unroll
      for (int rq = 0; rq < 4; ++rq){
        uint2 v0, v1;
        v0.x = pkbf(acc0[4*rq+0], acc0[4*rq+1]); v0.y = pkbf(acc0[4*rq+2], acc0[4*rq+3]);
        v1.x = pkbf(acc1[4*rq+0], acc1[4*rq+1]); v1.y = pkbf(acc1[4*rq+2], acc1[4*rq+3]);
        *(uint2*)(sm + KOFF + (size_t)jrow*KSTR +      (8*rq + 4*half)*2) = v0;
        *(uint2*)(sm + KOFF + (size_t)jrow*KSTR + 64 + (8*rq + 4*half)*2) = v1;
      }
    } else {
      const char* B0 = sm + WOFF + (size_t)(128 + l31)*WSTR;
      const char* B1 = sm + WOFF + (size_t)(160 + l31)*WSTR;
#pragma unroll
      for (int ks = 0; ks < 8; ++ks){
        bf16x8 a  = xfrag<XBF>(X, Xbf, grow, ks, coff, half);
        bf16x8 b0 = *(const bf16x8*)(B0 + ks*32 + coff);
        bf16x8 b1 = *(const bf16x8*)(B1 + ks*32 + coff);
        acc0 = MFMA32(a, b0, acc0);
        acc1 = MFMA32(a, b1, acc1);
      }
#pragma unroll
      for (int rq = 0; rq < 4; ++rq){
        uint2 v0, v1;
        v0.x = pkbf(acc0[4*rq+0], acc0[4*rq+1]); v0.y = pkbf(acc0[4*rq+2], acc0[4*rq+3]);
        v1.x = pkbf(acc1[4*rq+0], acc1[4*rq+1]); v1.y = pkbf(acc1[4*rq+2], acc1[4*rq+3]);
        *(uint2*)(sm + VTOFF + (size_t)(     l31)*VTSTR + (jt*32 + 8*rq + 4*half)*2) = v0;
        *(uint2*)(sm + VTOFF + (size_t)(32 + l31)*VTSTR + (jt*32 + 8*rq + 4*half)*2) = v1;
      }
    }
  }
  __syncthreads();

  // ================= phase 2: 10 q-tile wave-tasks over 8 waves ===============
  for (int rep = 0; rep < 2; ++rep){
    const int qt = w + 8*rep;
    if (qt >= 10) break;
    const int q = qt*32 + l31;
    // ---- Q-proj: D col = q, rows = d
    f32x16 qa0 = z16(), qa1 = z16();
#pragma unroll
    for (int ks = 0; ks < 8; ++ks){
      bf16x8 b  = xfrag<XBF>(X, Xbf, i*NN + q, ks, coff, half);
      bf16x8 a0 = *(const bf16x8*)(sm + WOFF + (size_t)(     l31)*WSTR + ks*32 + coff);
      bf16x8 a1 = *(const bf16x8*)(sm + WOFF + (size_t)(32 + l31)*WSTR + ks*32 + coff);
      qa0 = MFMA32(a0, b, qa0);
      qa1 = MFMA32(a1, b, qa1);
    }
    // ---- build qf[4] (B-frags over d) in-register from D-layout via lswap
    bf16x8 qf[4];
    {
      unsigned a0 = pkbf(qa0[0],qa0[1]),  a0b = pkbf(qa0[2],qa0[3]);
      unsigned a1 = pkbf(qa0[4],qa0[5]),  a1b = pkbf(qa0[6],qa0[7]);
      unsigned a2 = pkbf(qa0[8],qa0[9]),  a2b = pkbf(qa0[10],qa0[11]);
      unsigned a3 = pkbf(qa0[12],qa0[13]),a3b = pkbf(qa0[14],qa0[15]);
      unsigned b0 = pkbf(qa1[0],qa1[1]),  b0b = pkbf(qa1[2],qa1[3]);
      unsigned b1 = pkbf(qa1[4],qa1[5]),  b1b = pkbf(qa1[6],qa1[7]);
      unsigned b2 = pkbf(qa1[8],qa1[9]),  b2b = pkbf(qa1[10],qa1[11]);
      unsigned b3 = pkbf(qa1[12],qa1[13]),b3b = pkbf(qa1[14],qa1[15]);
      u32x2 s0 = lswap(a0,a1), s0b = lswap(a0b,a1b);
      u32x2 s1 = lswap(a2,a3), s1b = lswap(a2b,a3b);
      u32x2 s2 = lswap(b0,b1), s2b = lswap(b0b,b1b);
      u32x2 s3 = lswap(b2,b3), s3b = lswap(b2b,b3b);
      u32x4 f;
      f[0]=s0[0]; f[1]=s0b[0]; f[2]=s0[1]; f[3]=s0b[1]; qf[0]=__builtin_bit_cast(bf16x8,f);
      f[0]=s1[0]; f[1]=s1b[0]; f[2]=s1[1]; f[3]=s1b[1]; qf[1]=__builtin_bit_cast(bf16x8,f);
      f[0]=s2[0]; f[1]=s2b[0]; f[2]=s2[1]; f[3]=s2b[1]; qf[2]=__builtin_bit_cast(bf16x8,f);
      f[0]=s3[0]; f[1]=s3b[0]; f[2]=s3[1]; f[3]=s3b[1]; qf[3]=__builtin_bit_cast(bf16x8,f);
    }
    // ---- scores^T: S[j][q], D col = q = l31, rows = j
    f32x16 S[10];
#pragma unroll
    for (int jt = 0; jt < 10; ++jt) S[jt] = z16();
    __builtin_amdgcn_s_setprio(1);
#pragma unroll
    for (int jt = 0; jt < 10; ++jt){
#pragma unroll
      for (int c = 0; c < 4; ++c){
        bf16x8 a = *(const bf16x8*)(sm + KOFF + (size_t)(jt*32 + l31)*KSTR + c*32 + coff);
        S[jt] = MFMA32(a, qf[c], S[jt]);
      }
    }
    __builtin_amdgcn_s_setprio(0);
    // ---- scale + bias (coalesced j-grouped layout) + softmax over j
    const float4* Bq = (const float4*)(Bws + (size_t)h*NPAIR);
    float m = -3.0e38f;
#pragma unroll
    for (int jt = 0; jt < 10; ++jt){
      float mj = -3.0e38f;
#pragma unroll
      for (int rq = 0; rq < 4; ++rq){
        float4 bv = Bq[(jt*8 + 2*rq + half)*NN + q];
        float v0 = S[jt][4*rq+0]*SCL2 + bv.x;
        float v1 = S[jt][4*rq+1]*SCL2 + bv.y;
        float v2 = S[jt][4*rq+2]*SCL2 + bv.z;
        float v3 = S[jt][4*rq+3]*SCL2 + bv.w;
        S[jt][4*rq+0]=v0; S[jt][4*rq+1]=v1; S[jt][4*rq+2]=v2; S[jt][4*rq+3]=v3;
        mj = fmaxf(mj, fmaxf(fmaxf(v0,v1), fmaxf(v2,v3)));
      }
      m = fmaxf(m, mj);
    }
    {
      unsigned mu = __builtin_bit_cast(unsigned, m);
      u32x2 mm = lswap(mu, mu);
      m = fmaxf(__builtin_bit_cast(float, mm[0]), __builtin_bit_cast(float, mm[1]));
    }
    float l = 0.0f;
#pragma unroll
    for (int jt = 0; jt < 10; ++jt){
      float t0 = 0.f, t1 = 0.f, t2 = 0.f, t3 = 0.f;
#pragma unroll
      for (int k = 0; k < 4; ++k){
        float e0 = ex2(S[jt][4*k+0] - m);
        float e1 = ex2(S[jt][4*k+1] - m);
        float e2 = ex2(S[jt][4*k+2] - m);
        float e3 = ex2(S[jt][4*k+3] - m);
        S[jt][4*k+0]=e0; S[jt][4*k+1]=e1; S[jt][4*k+2]=e2; S[jt][4*k+3]=e3;
        t0 += e0; t1 += e1; t2 += e2; t3 += e3;
      }
      l += (t0 + t1) + (t2 + t3);
    }
    {
      unsigned lu = __builtin_bit_cast(unsigned, l);
      u32x2 ll = lswap(lu, lu);
      l = __builtin_bit_cast(float, ll[0]) + __builtin_bit_cast(float, ll[1]);
    }
    const float rl = 1.0f / l;
    // ---- PV: O^T[d][q] += Vt[d][j] * P^T[j][q]; P-frags via lswap.
    f32x16 o0 = z16(), o1 = z16();
#pragma unroll
    for (int jt = 0; jt < 10; ++jt){
      unsigned P0a = pkbf(S[jt][0], S[jt][1]),  P0b = pkbf(S[jt][2], S[jt][3]);
      unsigned P1a = pkbf(S[jt][4], S[jt][5]),  P1b = pkbf(S[jt][6], S[jt][7]);
      unsigned P2a = pkbf(S[jt][8], S[jt][9]),  P2b = pkbf(S[jt][10],S[jt][11]);
      unsigned P3a = pkbf(S[jt][12],S[jt][13]), P3b = pkbf(S[jt][14],S[jt][15]);
      u32x2 e0 = lswap(P0a,P1a), e1 = lswap(P0b,P1b);
      u32x2 d0 = lswap(P2a,P3a), d1 = lswap(P2b,P3b);
      u32x4 fe, fo;
      fe[0]=e0[0]; fe[1]=e1[0]; fe[2]=e0[1]; fe[3]=e1[1];
      fo[0]=d0[0]; fo[1]=d1[0]; fo[2]=d0[1]; fo[3]=d1[1];
      bf16x8 pe = __builtin_bit_cast(bf16x8, fe);
      bf16x8 po = __builtin_bit_cast(bf16x8, fo);
      bf16x8 va0e = *(const bf16x8*)(sm + VTOFF + (size_t)(     l31)*VTSTR + jt*64 + coff);
      bf16x8 va1e = *(const bf16x8*)(sm + VTOFF + (size_t)(32 + l31)*VTSTR + jt*64 + coff);
      bf16x8 va0o = *(const bf16x8*)(sm + VTOFF + (size_t)(     l31)*VTSTR + jt*64 + 32 + coff);
      bf16x8 va1o = *(const bf16x8*)(sm + VTOFF + (size_t)(32 + l31)*VTSTR + jt*64 + 32 + coff);
      __builtin_amdgcn_s_setprio(1);
      o0 = MFMA32(va0e, pe, o0);
      o1 = MFMA32(va1e, pe, o1);
      o0 = MFMA32(va0o, po, o0);
      o1 = MFMA32(va1o, po, o1);
      __builtin_amdgcn_s_setprio(0);
    }
    // ---- epilogue: blocked Attn2 layout, full 512B wave-stores
    const size_t rowblk = (size_t)i*10 + qt;
    char* Ob = (char*)AttnOut;
#pragma unroll
    for (int rq = 0; rq < 4; ++rq){
      uint2 v0, v1;
      v0.x = pkbf(o0[4*rq+0]*rl, o0[4*rq+1]*rl); v0.y = pkbf(o0[4*rq+2]*rl, o0[4*rq+3]*rl);
      v1.x = pkbf(o1[4*rq+0]*rl, o1[4*rq+1]*rl); v1.y = pkbf(o1[4*rq+2]*rl, o1[4*rq+3]*rl);
      *(uint2*)(Ob + ((rowblk*32 + h*8     + rq)*32 + l31)*16 + 8*half) = v0;
      *(uint2*)(Ob + ((rowblk*32 + h*8 + 4 + rq)*32 + l31)*16 + 8*half) = v1;
    }
  }
}

// ---------------------------------------------------------------------------
// proj: Out = Attn @ Wout + bout.  LDS = W^T only (67.6 KB -> 2 WG/CU).
// A-frags from blocked Attn2 layout (contiguous 512B wave-reads). Each wave
// reads only its own 32 rows then overwrites them (alias-safe in d_out).
// ---------------------------------------------------------------------------
#define B_WSTR 528
#define LDS_P  67584

template<bool WT>
__global__ void __launch_bounds__(256, 2) proj_kernel(const unsigned short* Attn,
                                                      const float* __restrict__ Wout,
                                                      const float* __restrict__ bout,
                                                      float* Out,
                                                      const unsigned short* __restrict__ Woutt){
  extern __shared__ char sm[];
  const int tid = threadIdx.x, w = tid>>6, lane = tid&63, half = lane>>5, l31 = lane&31;
  const int coff = half*16;
  const size_t r0 = (size_t)blockIdx.x * 128;
  if (WT){                                   // coalesced copy of pre-transposed W
    for (int idx = tid; idx < 128*32; idx += 256){
      const int col = idx >> 5, seg = idx & 31;
      u32x4 v = *(const u32x4*)(Woutt + (size_t)col*INNERD + seg*8);
      *(u32x4*)(sm + (size_t)col*B_WSTR + seg*16) = v;
    }
  } else if (tid < 128){                     // legacy on-the-fly transpose
    const int col = tid;
    char* dst = sm + (size_t)col*B_WSTR;
    for (int d0 = 0; d0 < 256; d0 += 8){
      u32x4 v;
      v[0] = pkbf(Wout[(size_t)(d0+0)*DIMD + col], Wout[(size_t)(d0+1)*DIMD + col]);
      v[1] = pkbf(Wout[(size_t)(d0+2)*DIMD + col], Wout[(size_t)(d0+3)*DIMD + col]);
      v[2] = pkbf(Wout[(size_t)(d0+4)*DIMD + col], Wout[(size_t)(d0+5)*DIMD + col]);
      v[3] = pkbf(Wout[(size_t)(d0+6)*DIMD + col], Wout[(size_t)(d0+7)*DIMD + col]);
      *(u32x4*)(dst + d0*2) = v;
    }
  }
  __syncthreads();
  f32x16 acc[4];
#pragma unroll
  for (int nt = 0; nt < 4; ++nt){
    float bv = bout[nt*32 + l31];
#pragma unroll
    for (int k = 0; k < 16; ++k) acc[nt][k] = bv;
  }
  const size_t rowblk = (size_t)blockIdx.x*4 + w;
  const char* Ab = (const char*)Attn;
#pragma unroll
  for (int ks = 0; ks < 16; ++ks){
    bf16x8 a = *(const bf16x8*)(Ab + ((rowblk*32 + ks*2 + half)*32 + l31)*16);
#pragma unroll
    for (int nt = 0; nt < 4; ++nt){
      bf16x8 b = *(const bf16x8*)(sm + (size_t)(nt*32 + l31)*B_WSTR + ks*32 + coff);
      acc[nt] = MFMA32(a, b, acc[nt]);
    }
  }
#pragma unroll
  for (int nt = 0; nt < 4; ++nt){
    const int c = nt*32 + l31;
#pragma unroll
    for (int rq = 0; rq < 4; ++rq){
#pragma unroll
      for (int r = 0; r < 4; ++r){
        const int rr = w*32 + 8*rq + 4*half + r;
        Out[(r0 + rr)*DIMD + c] = acc[nt][4*rq + r];
      }
    }
  }
}

// ---------------------------------------------------------------------------
extern "C" void kernel_launch(void* const* d_in, const int* in_sizes, int n_in,
                              void* d_out, int out_size, void* d_ws, size_t ws_size,
                              hipStream_t stream){
  const float* X     = (const float*)d_in[0];
  const float* Wqkv  = (const float*)d_in[1];
  const float* Wout  = (const float*)d_in[2];
  const float* bout  = (const float*)d_in[3];
  const float* Wbias = (const float*)d_in[4];
  float* Out = (float*)d_out;

  // ws layout: Bws fp32 [0,1638400) | Xbf bf16 [1638400,27852800)
  //            | Wqkvt [27852800,28049408) | Woutt [28049408,28114944)
  float*          Bws   = (float*)d_ws;
  unsigned short* Xbf   = (unsigned short*)((char*)d_ws + 1638400);
  unsigned*       XbfU  = (unsigned*)Xbf;
  unsigned short* Wqkvt = (unsigned short*)((char*)d_ws + 27852800);
  unsigned short* Woutt = (unsigned short*)((char*)d_ws + 28049408);
  const bool use_bf = (ws_size >= (size_t)28049408);
  const bool use_wt = (ws_size >= (size_t)28114944);

  unsigned short* Attn = (unsigned short*)d_out;   // bf16 intermediate lives in d_out

  if (use_bf){
    (void)hipFuncSetAttribute((const void*)attn_kernel<true>,
                              hipFuncAttributeMaxDynamicSharedMemorySize, LDS_A);
    x2bf_bias<true><<<NPAIR/16, 256, 0, stream>>>(X, Wbias, Bws, XbfU);
    wpack<<<use_wt ? 512 : 384, 256, 0, stream>>>(Wqkv, Wqkvt, Wout, Woutt);
    attn_kernel<true><<<dim3(NHEADS, NN), 512, LDS_A, stream>>>(X, Xbf, Wqkv, Wqkvt, Bws, Attn);
  } else {
    (void)hipFuncSetAttribute((const void*)attn_kernel<false>,
                              hipFuncAttributeMaxDynamicSharedMemorySize, LDS_A);
    x2bf_bias<false><<<NPAIR/16, 256, 0, stream>>>(X, Wbias, Bws, nullptr);
    attn_kernel<false><<<dim3(NHEADS, NN), 512, LDS_A, stream>>>(X, nullptr, Wqkv, nullptr, Bws, Attn);
  }
  if (use_wt){
    (void)hipFuncSetAttribute((const void*)proj_kernel<true>,
                              hipFuncAttributeMaxDynamicSharedMemorySize, LDS_P);
    proj_kernel<true><<<NPAIR/128, 256, LDS_P, stream>>>(Attn, Wout, bout, Out, Woutt);
  } else {
    (void)hipFuncSetAttribute((const void*)proj_kernel<false>,
                              hipFuncAttributeMaxDynamicSharedMemorySize, LDS_P);
    proj_kernel<false><<<NPAIR/128, 256, LDS_P, stream>>>(Attn, Wout, bout, Out, nullptr);
  }
}